// Round 1
// baseline (1500.602 us; speedup 1.0000x reference)
//
#include <hip/hip_runtime.h>
#include <math.h>

// Sizes (fixed by the reference problem)
#define NV 200     // N nodes
#define DEG 199
#define HID 96
#define KG 20      // groups / one-hot width
#define MG 10      // group size
#define AJR 30
#define NH 4
#define HD 118     // HID + 2 + K
#define DM 472     // NH*HD
#define NN 40000   // N*N

// Workspace layout (floats). Total 19,772,552 floats = 79.1 MB.
#define WS_BASE   0
#define WS_H1     19200
#define WS_H2     38400
#define WS_HFULL  57600
#define WS_GMEAN  81200
#define WS_W0S    83560
#define WS_W1S    139256
#define WS_KHF    194952
#define WS_VHF    289352
#define WS_B1     383752
#define WS_B2     478152
#define WS_SC1    572552
#define WS_SC2    732552
#define WS_O      892552

// Output layout (floats)
#define OFF_H   18880000
#define OFF_HF  18899200
#define OFF_Q   18922800

// ---------------------------------------------------------------------------
// A: iteration-invariant part of the GCN update:
// base = x@l0w+l0b + label@l1w+l1b + l2b + l3b + n1_e@l4w+l4b + n2_e@l5w+l5b
// n1_e = top-30 (desc) of d*t0 ; n2_e = the 9 same-group d's sorted desc
// ---------------------------------------------------------------------------
__global__ __launch_bounds__(256) void k_base(
    const float* __restrict__ x, const float* __restrict__ dmat,
    const float* __restrict__ label,
    const float* __restrict__ l0w, const float* __restrict__ l0b,
    const float* __restrict__ l1w, const float* __restrict__ l1b,
    const float* __restrict__ l2b, const float* __restrict__ l3b,
    const float* __restrict__ l4w, const float* __restrict__ l4b,
    const float* __restrict__ l5w, const float* __restrict__ l5b,
    float* __restrict__ base) {
  int i = blockIdx.x; int t = threadIdx.x;
  int g = i / MG;
  __shared__ float sv[256];
  __shared__ float sn2[9];
  float v = -1.0f;
  if (t < DEG) {
    int u = (t < i) ? t : t + 1;
    if (u / MG != g) v = dmat[i * DEG + t];  // d*t0 (cross-group), else sink
  }
  sv[t] = v;
  __syncthreads();
  // bitonic sort, descending, 256 elements
  for (int k2 = 2; k2 <= 256; k2 <<= 1) {
    for (int jj = k2 >> 1; jj > 0; jj >>= 1) {
      int ixj = t ^ jj;
      if (ixj > t) {
        float a = sv[t], b = sv[ixj];
        bool sw = ((t & k2) == 0) ? (a < b) : (a > b);
        if (sw) { sv[t] = b; sv[ixj] = a; }
      }
      __syncthreads();
    }
  }
  if (t == 0) {
    // same-group edge slots are exactly j = 10g .. 10g+8 (contiguous)
    float tmp[9];
    for (int q = 0; q < 9; q++) tmp[q] = dmat[i * DEG + MG * g + q];
    for (int a2 = 1; a2 < 9; a2++) {
      float key = tmp[a2]; int b2 = a2 - 1;
      while (b2 >= 0 && tmp[b2] < key) { tmp[b2 + 1] = tmp[b2]; b2--; }
      tmp[b2 + 1] = key;
    }
    for (int q = 0; q < 9; q++) sn2[q] = tmp[q];
  }
  __syncthreads();
  if (t < HID) {
    float acc = l0b[t] + l1b[t] + l2b[t] + l3b[t] + l4b[t] + l5b[t];
    acc += x[i * 2 + 0] * l0w[t] + x[i * 2 + 1] * l0w[HID + t];
    for (int k = 0; k < KG; k++) acc += label[i * KG + k] * l1w[k * HID + t];
    for (int q = 0; q < AJR; q++) acc += sv[q] * l4w[q * HID + t];
    for (int q = 0; q < 9; q++) acc += sn2[q] * l5w[q * HID + t];
    base[i * HID + t] = acc;
  }
}

// ---------------------------------------------------------------------------
// B: one GCN step: h_out = relu(base + n1_v@l2w + n2_v@l3w)
// ---------------------------------------------------------------------------
__global__ __launch_bounds__(192) void k_gcn(
    const float* __restrict__ hin, const float* __restrict__ base,
    const float* __restrict__ w, const float* __restrict__ l2w,
    const float* __restrict__ l3w, float* __restrict__ hout) {
  int i = blockIdx.x; int t = threadIdx.x;
  int g = i / MG;
  __shared__ float n1[HID], n2[HID];
  if (t < HID) {
    float acc = 0.f, wsum = 0.f;
    for (int j = 0; j < DEG; j++) {
      int u = (j < i) ? j : j + 1;
      if (u / MG != g) {
        float wj = w[i * DEG + j];
        acc += wj * hin[u * HID + t];
        wsum += wj;
      }
    }
    n1[t] = acc / wsum;
  } else if (t < 2 * HID) {
    int dd = t - HID;
    float acc = 0.f, wsum = 0.f;
    for (int u = MG * g; u < MG * g + MG; u++) {
      if (u == i) continue;
      int j = (u < i) ? u : u - 1;
      float wj = w[i * DEG + j];
      acc += wj * hin[u * HID + dd];
      wsum += wj;
    }
    n2[dd] = acc / wsum;
  }
  __syncthreads();
  if (t < HID) {
    float acc = base[i * HID + t];
    for (int dd = 0; dd < HID; dd++)
      acc += n1[dd] * l2w[dd * HID + t] + n2[dd] * l3w[dd * HID + t];
    hout[i * HID + t] = fmaxf(acc, 0.f);
  }
}

// ---------------------------------------------------------------------------
// C1: h_full = [h + pe[remain_step], x, label]; also emits h and h_full outputs
// ---------------------------------------------------------------------------
__global__ __launch_bounds__(128) void k_hfull(
    const float* __restrict__ h, const float* __restrict__ x,
    const float* __restrict__ label, const int* __restrict__ remain_step,
    float* __restrict__ hfull, float* __restrict__ out_h,
    float* __restrict__ out_hf) {
  int i = blockIdx.x; int t = threadIdx.x;
  if (t < HD) {
    float v;
    if (t < HID) {
      int p = *remain_step;
      int t2 = t & ~1;
      float div = expf(-(float)t2 * (logf(10000.f) / (float)HID));
      float ang = (float)p * div;
      float pe = (t & 1) ? cosf(ang) : sinf(ang);
      float hv = h[i * HID + t];
      out_h[i * HID + t] = hv;
      v = hv + pe;
    } else if (t < HID + 2) {
      v = x[i * 2 + (t - HID)];
    } else {
      v = label[i * KG + (t - HID - 2)];
    }
    hfull[i * HD + t] = v;
    out_hf[i * HD + t] = v;
  }
}

// C2: gmean[g][d] = mean over the 10 nodes of group g of h_full (== gc.T rows)
__global__ __launch_bounds__(128) void k_gmean(
    const float* __restrict__ hfull, float* __restrict__ gmean) {
  int g = blockIdx.x; int t = threadIdx.x;
  if (t < HD) {
    float s = 0.f;
    for (int q = 0; q < MG; q++) s += hfull[(g * MG + q) * HD + t];
    gmean[g * HD + t] = s * 0.1f;
  }
}

// D1: W{0,1}sum[d][c] = sum of the 4 118-row blocks of mha_w{0,1} (kv tiling)
__global__ __launch_bounds__(256) void k_wsum(
    const float* __restrict__ w0, const float* __restrict__ w1,
    float* __restrict__ W0s, float* __restrict__ W1s) {
  int idx = blockIdx.x * blockDim.x + threadIdx.x;
  if (idx < HD * DM) {
    int dp = idx / DM, c = idx - dp * DM;
    W0s[idx] = w0[dp * DM + c] + w0[(HD + dp) * DM + c] +
               w0[(2 * HD + dp) * DM + c] + w0[(3 * HD + dp) * DM + c];
    W1s[idx] = w1[dp * DM + c] + w1[(HD + dp) * DM + c] +
               w1[(2 * HD + dp) * DM + c] + w1[(3 * HD + dp) * DM + c];
  }
}

// D2: khf[k][c] = h_full[k]@W0sum + b0 ; vhf likewise with W1sum/b1
__global__ __launch_bounds__(256) void k_kv(
    const float* __restrict__ hfull, const float* __restrict__ W0s,
    const float* __restrict__ b0v, const float* __restrict__ W1s,
    const float* __restrict__ b1v, float* __restrict__ khf,
    float* __restrict__ vhf) {
  int i = blockIdx.x; int t = threadIdx.x;
  __shared__ float hr[HD];
  if (t < HD) hr[t] = hfull[i * HD + t];
  __syncthreads();
  for (int c = t; c < DM; c += 256) {
    float a0 = b0v[c], a1 = b1v[c];
    for (int dd = 0; dd < HD; dd++) {
      float hv = hr[dd];
      a0 += hv * W0s[dd * DM + c];
      a1 += hv * W1s[dd * DM + c];
    }
    khf[i * DM + c] = a0;
    vhf[i * DM + c] = a1;
  }
}

// D3: B1[i] = h_full[i]@w0[0:118] + gmean[grp i]@w0[236:354]
//     B2[j] = h_full[j]@w0[118:236] + gmean[grp j]@w0[354:472] + b0
__global__ __launch_bounds__(256) void k_B(
    const float* __restrict__ hfull, const float* __restrict__ gmean,
    const float* __restrict__ w0, const float* __restrict__ b0v,
    float* __restrict__ B1, float* __restrict__ B2) {
  int i = blockIdx.x; int t = threadIdx.x; int g = i / MG;
  __shared__ float hr[HD], gr[HD];
  if (t < HD) { hr[t] = hfull[i * HD + t]; gr[t] = gmean[g * HD + t]; }
  __syncthreads();
  for (int c = t; c < DM; c += 256) {
    float a1 = 0.f, a2 = b0v[c];
    for (int dd = 0; dd < HD; dd++) {
      a1 += hr[dd] * w0[dd * DM + c] + gr[dd] * w0[(2 * HD + dd) * DM + c];
      a2 += hr[dd] * w0[(HD + dd) * DM + c] + gr[dd] * w0[(3 * HD + dd) * DM + c];
    }
    B1[i * DM + c] = a1;
    B2[i * DM + c] = a2;
  }
}

// D4: SC1[h][i][k] = B1[i]|head h . khf[k]|head h ; SC2 likewise from B2
__global__ __launch_bounds__(256) void k_SC(
    const float* __restrict__ B1, const float* __restrict__ B2,
    const float* __restrict__ khf, float* __restrict__ SC1,
    float* __restrict__ SC2) {
  int i = blockIdx.x; int t = threadIdx.x;
  __shared__ float b1r[DM], b2r[DM];
  for (int c = t; c < DM; c += 256) { b1r[c] = B1[i * DM + c]; b2r[c] = B2[i * DM + c]; }
  __syncthreads();
  for (int p = t; p < NH * NV; p += 256) {
    int h = p / NV, k = p - h * NV;
    float s1a = 0.f, s2a = 0.f;
    for (int dd = 0; dd < HD; dd++) {
      float kv = khf[k * DM + h * HD + dd];
      s1a += b1r[h * HD + dd] * kv;
      s2a += b2r[h * HD + dd] * kv;
    }
    SC1[h * NN + i * NV + k] = s1a;
    SC2[h * NN + i * NV + k] = s2a;
  }
}

// ---------------------------------------------------------------------------
// E: attention. Block (i, head, d-half). scores(j,k) = (SC1[i,k]+SC2[j,k])*scale,
// softmax over k, O[i*200+j][head,dslice] = P @ vh.
// LDS: vh slice (200x60 fp32, 48KB) + P (16x200, 12.8KB) + s1 (0.8KB) = 61.6KB
// ---------------------------------------------------------------------------
__global__ __launch_bounds__(256) void k_attn(
    const float* __restrict__ SC1, const float* __restrict__ SC2,
    const float* __restrict__ vhf, float* __restrict__ O) {
  int i = blockIdx.x, h = blockIdx.y, half = blockIdx.z;
  int d0 = half * 59;
  const int ND = 59;
  int t = threadIdx.x;
  __shared__ float vh_s[NV * 60];
  __shared__ float P[16 * NV];
  __shared__ float s1[NV];
  for (int e = t; e < NV * ND; e += 256) {
    int k = e / ND, dd = e - k * ND;
    vh_s[k * 60 + dd] = vhf[k * DM + h * HD + d0 + dd];
  }
  for (int k = t; k < NV; k += 256) s1[k] = SC1[h * NN + i * NV + k];
  __syncthreads();
  const float scale = 1.0f / sqrtf((float)HD);
  int tr = t >> 4, tl = t & 15;   // softmax: 16 rows x 16 lanes
  int tj = t >> 6, td = t & 63;   // PV: 4 row-groups x 64 dim lanes
  for (int jc = 0; jc < NV; jc += 16) {
    int rem = NV - jc; if (rem > 16) rem = 16;
    float m = -1e30f;
    if (tr < rem) {
      const float* sc2row = SC2 + h * NN + (jc + tr) * NV;
      for (int k = tl; k < NV; k += 16) {
        float s = (s1[k] + sc2row[k]) * scale;
        P[tr * NV + k] = s;
        m = fmaxf(m, s);
      }
    }
    m = fmaxf(m, __shfl_xor(m, 1));
    m = fmaxf(m, __shfl_xor(m, 2));
    m = fmaxf(m, __shfl_xor(m, 4));
    m = fmaxf(m, __shfl_xor(m, 8));
    float l = 0.f;
    if (tr < rem) {
      for (int k = tl; k < NV; k += 16) {
        float e = expf(P[tr * NV + k] - m);
        P[tr * NV + k] = e;
        l += e;
      }
    }
    l += __shfl_xor(l, 1); l += __shfl_xor(l, 2);
    l += __shfl_xor(l, 4); l += __shfl_xor(l, 8);
    if (tr < rem) {
      float rinv = 1.0f / l;
      for (int k = tl; k < NV; k += 16) P[tr * NV + k] *= rinv;
    }
    __syncthreads();
    if (td < ND) {
      float a0 = 0.f, a1 = 0.f, a2 = 0.f, a3 = 0.f;
      for (int k = 0; k < NV; k++) {
        float v = vh_s[k * 60 + td];
        a0 += P[(tj * 4 + 0) * NV + k] * v;
        a1 += P[(tj * 4 + 1) * NV + k] * v;
        a2 += P[(tj * 4 + 2) * NV + k] * v;
        a3 += P[(tj * 4 + 3) * NV + k] * v;
      }
      float av[4] = {a0, a1, a2, a3};
      int bb = i * NV + jc;
      for (int rr = 0; rr < 4; rr++) {
        int r = tj * 4 + rr;
        if (r < rem) O[(size_t)(bb + r) * DM + h * HD + d0 + td] = av[rr];
      }
    }
    __syncthreads();
  }
}

// ---------------------------------------------------------------------------
// F: S[b] = (O[b] + O[mirror(b)]) @ w3 + 2*b3. Tiled 128x128x16, 8x8 microtile.
// ---------------------------------------------------------------------------
__global__ __launch_bounds__(256) void k_sgemm(
    const float* __restrict__ O, const float* __restrict__ w3,
    const float* __restrict__ b3, float* __restrict__ outS) {
  const int BM = 128, BN = 128, BK = 16;
  int c0 = blockIdx.x * BN, b0 = blockIdx.y * BM;
  __shared__ float As[BK][BM];
  __shared__ float Bs[BK][BN];
  int t = threadIdx.x;
  int ar = t >> 1, ak = (t & 1) * 8;
  int bk = t >> 4, bc = (t & 15) * 8;
  int ty = t >> 4, tx = t & 15;
  float acc[8][8];
#pragma unroll
  for (int y = 0; y < 8; y++)
#pragma unroll
    for (int xx = 0; xx < 8; xx++) acc[y][xx] = 0.f;
  int b = b0 + ar;
  int valid = (b < NN);
  int mb = 0;
  if (valid) { int ii = b / NV; int jj2 = b - ii * NV; mb = jj2 * NV + ii; }
  for (int k0 = 0; k0 < DM; k0 += BK) {
    float av[8], bv[8];
#pragma unroll
    for (int q = 0; q < 8; q++) {
      int kg = k0 + ak + q;
      av[q] = (valid && kg < DM)
                  ? (O[(size_t)b * DM + kg] + O[(size_t)mb * DM + kg])
                  : 0.f;
    }
#pragma unroll
    for (int q = 0; q < 8; q++) {
      int cg = c0 + bc + q;
      int kg = k0 + bk;
      bv[q] = (kg < DM && cg < DM) ? w3[kg * DM + cg] : 0.f;
    }
    __syncthreads();
#pragma unroll
    for (int q = 0; q < 8; q++) As[ak + q][ar] = av[q];
#pragma unroll
    for (int q = 0; q < 8; q++) Bs[bk][bc + q] = bv[q];
    __syncthreads();
#pragma unroll
    for (int kk = 0; kk < BK; kk++) {
      float a8[8], b8[8];
#pragma unroll
      for (int q = 0; q < 8; q++) a8[q] = As[kk][ty * 8 + q];
#pragma unroll
      for (int q = 0; q < 8; q++) b8[q] = Bs[kk][tx * 8 + q];
#pragma unroll
      for (int y = 0; y < 8; y++)
#pragma unroll
        for (int xx = 0; xx < 8; xx++) acc[y][xx] += a8[y] * b8[xx];
    }
  }
#pragma unroll
  for (int y = 0; y < 8; y++) {
    int bo = b0 + ty * 8 + y;
    if (bo < NN) {
#pragma unroll
      for (int xx = 0; xx < 8; xx++) {
        int c = c0 + tx * 8 + xx;
        if (c < DM) outS[(size_t)bo * DM + c] = acc[y][xx] + 2.0f * b3[c];
      }
    }
  }
}

// ---------------------------------------------------------------------------
// G: Q_sa = relu(S@v1+b1)@v2 + b2, 64 rows per block
// ---------------------------------------------------------------------------
__global__ __launch_bounds__(256) void k_qsa(
    const float* __restrict__ S, const float* __restrict__ v1w,
    const float* __restrict__ v1b, const float* __restrict__ v2w,
    const float* __restrict__ v2b, float* __restrict__ outQ) {
  __shared__ float Ss[64][9];
  __shared__ float V1s[8][48];
  __shared__ float Ts[64][49];
  int t = threadIdx.x;
  int b0 = blockIdx.x * 64;
  int ty = t >> 4, tx = t & 15;
  int lr = t >> 2, lk = (t & 3) * 2;
  float acc[4][3];
#pragma unroll
  for (int y = 0; y < 4; y++)
#pragma unroll
    for (int xx = 0; xx < 3; xx++) acc[y][xx] = 0.f;
  for (int k0 = 0; k0 < DM; k0 += 8) {
    __syncthreads();
    Ss[lr][lk] = S[(size_t)(b0 + lr) * DM + k0 + lk];
    Ss[lr][lk + 1] = S[(size_t)(b0 + lr) * DM + k0 + lk + 1];
    if (t < 192) {
      int e = t * 2; int kk = e / 48, c = e - kk * 48;
      V1s[kk][c] = v1w[(k0 + kk) * 48 + c];
      V1s[kk][c + 1] = v1w[(k0 + kk) * 48 + c + 1];
    }
    __syncthreads();
#pragma unroll
    for (int kk = 0; kk < 8; kk++) {
      float a0 = Ss[ty * 4 + 0][kk], a1 = Ss[ty * 4 + 1][kk],
            a2 = Ss[ty * 4 + 2][kk], a3 = Ss[ty * 4 + 3][kk];
      float w0_ = V1s[kk][tx * 3 + 0], w1_ = V1s[kk][tx * 3 + 1],
            w2_ = V1s[kk][tx * 3 + 2];
      acc[0][0] += a0 * w0_; acc[0][1] += a0 * w1_; acc[0][2] += a0 * w2_;
      acc[1][0] += a1 * w0_; acc[1][1] += a1 * w1_; acc[1][2] += a1 * w2_;
      acc[2][0] += a2 * w0_; acc[2][1] += a2 * w1_; acc[2][2] += a2 * w2_;
      acc[3][0] += a3 * w0_; acc[3][1] += a3 * w1_; acc[3][2] += a3 * w2_;
    }
  }
#pragma unroll
  for (int y = 0; y < 4; y++)
#pragma unroll
    for (int xx = 0; xx < 3; xx++)
      Ts[ty * 4 + y][tx * 3 + xx] = fmaxf(acc[y][xx] + v1b[tx * 3 + xx], 0.f);
  __syncthreads();
  if (t < 64) {
    float q = v2b[0];
    for (int c = 0; c < 48; c++) q += Ts[t][c] * v2w[c];
    outQ[b0 + t] = q;
  }
}

// ---------------------------------------------------------------------------
extern "C" void kernel_launch(void* const* d_in, const int* in_sizes, int n_in,
                              void* d_out, int out_size, void* d_ws,
                              size_t ws_size, hipStream_t stream) {
  const float* x = (const float*)d_in[0];
  const float* label = (const float*)d_in[1];
  const float* h0 = (const float*)d_in[2];
  const float* w = (const float*)d_in[3];
  const float* dmat = (const float*)d_in[4];
  const float* l0w = (const float*)d_in[5];
  const float* l0b = (const float*)d_in[6];
  const float* l1w = (const float*)d_in[7];
  const float* l1b = (const float*)d_in[8];
  const float* l2w = (const float*)d_in[9];
  const float* l2b = (const float*)d_in[10];
  const float* l3w = (const float*)d_in[11];
  const float* l3b = (const float*)d_in[12];
  const float* l4w = (const float*)d_in[13];
  const float* l4b = (const float*)d_in[14];
  const float* l5w = (const float*)d_in[15];
  const float* l5b = (const float*)d_in[16];
  const float* w0 = (const float*)d_in[17];
  const float* b0v = (const float*)d_in[18];
  const float* w1 = (const float*)d_in[19];
  const float* b1v = (const float*)d_in[20];
  const float* w3 = (const float*)d_in[21];
  const float* b3 = (const float*)d_in[22];
  const float* v1w = (const float*)d_in[23];
  const float* v1b = (const float*)d_in[24];
  const float* v2w = (const float*)d_in[25];
  const float* v2b = (const float*)d_in[26];
  // d_in[27] = gnn_step (==2, loop count hardcoded: it selects #launches which
  // cannot be read device-side during graph capture), d_in[28] = max_step (only
  // sizes the PE table; unused since PE is computed analytically)
  const int* remain_step = (const int*)d_in[29];

  float* ws = (float*)d_ws;  // requires ~79.1 MB of scratch
  float* base = ws + WS_BASE;
  float* h1 = ws + WS_H1;
  float* h2 = ws + WS_H2;
  float* hfull = ws + WS_HFULL;
  float* gmean = ws + WS_GMEAN;
  float* W0s = ws + WS_W0S;
  float* W1s = ws + WS_W1S;
  float* khf = ws + WS_KHF;
  float* vhf = ws + WS_VHF;
  float* B1 = ws + WS_B1;
  float* B2 = ws + WS_B2;
  float* SC1 = ws + WS_SC1;
  float* SC2 = ws + WS_SC2;
  float* O = ws + WS_O;

  float* outS = (float*)d_out;
  float* outH = outS + OFF_H;
  float* outHF = outS + OFF_HF;
  float* outQ = outS + OFF_Q;

  k_base<<<NV, 256, 0, stream>>>(x, dmat, label, l0w, l0b, l1w, l1b, l2b, l3b,
                                 l4w, l4b, l5w, l5b, base);
  k_gcn<<<NV, 192, 0, stream>>>(h0, base, w, l2w, l3w, h1);
  k_gcn<<<NV, 192, 0, stream>>>(h1, base, w, l2w, l3w, h2);
  k_hfull<<<NV, 128, 0, stream>>>(h2, x, label, remain_step, hfull, outH, outHF);
  k_gmean<<<KG, 128, 0, stream>>>(hfull, gmean);
  k_wsum<<<(HD * DM + 255) / 256, 256, 0, stream>>>(w0, w1, W0s, W1s);
  k_kv<<<NV, 256, 0, stream>>>(hfull, W0s, b0v, W1s, b1v, khf, vhf);
  k_B<<<NV, 256, 0, stream>>>(hfull, gmean, w0, b0v, B1, B2);
  k_SC<<<NV, 256, 0, stream>>>(B1, B2, khf, SC1, SC2);
  k_attn<<<dim3(NV, NH, 2), 256, 0, stream>>>(SC1, SC2, vhf, O);
  k_sgemm<<<dim3(4, 313), 256, 0, stream>>>(O, w3, b3, outS);
  k_qsa<<<NN / 64, 256, 0, stream>>>(outS, v1w, v1b, v2w, v2b, outQ);
}

// Round 2
// 1027.883 us; speedup vs baseline: 1.4599x; 1.4599x over previous
//
#include <hip/hip_runtime.h>
#include <math.h>

typedef unsigned short ushort;
typedef unsigned int uint;

// Sizes (fixed by the reference problem)
#define NV 200     // N nodes
#define DEG 199
#define HID 96
#define KG 20      // groups / one-hot width
#define MG 10      // group size
#define AJR 30
#define NH 4
#define HD 118     // HID + 2 + K
#define DM 472     // NH*HD
#define NN 40000   // N*N

// Workspace layout (float units). Total footprint = 19,772,552 floats = 79.1 MB
// (identical to the round-1 proven footprint).
#define WS_BASE   0
#define WS_H1     19200
#define WS_H2     38400
#define WS_HFULL  57600
#define WS_GMEAN  81200
#define WS_W0S    83560
#define WS_W1S    139256
#define WS_KHF    194952
#define WS_VHF    289352
#define WS_B1     383752
#define WS_B2     478152
#define WS_SC1    572552   // after k_attn, this slot is reused for w3T (bf16)
#define WS_SC2    732552
#define WS_OB     892552   // O in bf16: 40000x472 ushort = 9,440,000 floats
#define WS_OSUM   10332552 // Osum bf16: 40000x472 ushort = 9,440,000 floats

// Output layout (floats)
#define OFF_H   18880000
#define OFF_HF  18899200
#define OFF_Q   18922800

typedef __attribute__((ext_vector_type(8))) short short8v;
typedef __attribute__((ext_vector_type(4))) float float4v;

__device__ __forceinline__ float bf2f(uint u) {
  return __uint_as_float(u << 16);
}
__device__ __forceinline__ ushort f2bf(float f) {
  uint u = __float_as_uint(f);
  uint r = (u + 0x7fffu + ((u >> 16) & 1u)) >> 16;  // round-to-nearest-even
  return (ushort)r;
}

// ---------------------------------------------------------------------------
// A: iteration-invariant part of the GCN update
// ---------------------------------------------------------------------------
__global__ __launch_bounds__(256) void k_base(
    const float* __restrict__ x, const float* __restrict__ dmat,
    const float* __restrict__ label,
    const float* __restrict__ l0w, const float* __restrict__ l0b,
    const float* __restrict__ l1w, const float* __restrict__ l1b,
    const float* __restrict__ l2b, const float* __restrict__ l3b,
    const float* __restrict__ l4w, const float* __restrict__ l4b,
    const float* __restrict__ l5w, const float* __restrict__ l5b,
    float* __restrict__ base) {
  int i = blockIdx.x; int t = threadIdx.x;
  int g = i / MG;
  __shared__ float sv[256];
  __shared__ float sn2[9];
  float v = -1.0f;
  if (t < DEG) {
    int u = (t < i) ? t : t + 1;
    if (u / MG != g) v = dmat[i * DEG + t];
  }
  sv[t] = v;
  __syncthreads();
  for (int k2 = 2; k2 <= 256; k2 <<= 1) {
    for (int jj = k2 >> 1; jj > 0; jj >>= 1) {
      int ixj = t ^ jj;
      if (ixj > t) {
        float a = sv[t], b = sv[ixj];
        bool sw = ((t & k2) == 0) ? (a < b) : (a > b);
        if (sw) { sv[t] = b; sv[ixj] = a; }
      }
      __syncthreads();
    }
  }
  if (t == 0) {
    float tmp[9];
    for (int q = 0; q < 9; q++) tmp[q] = dmat[i * DEG + MG * g + q];
    for (int a2 = 1; a2 < 9; a2++) {
      float key = tmp[a2]; int b2 = a2 - 1;
      while (b2 >= 0 && tmp[b2] < key) { tmp[b2 + 1] = tmp[b2]; b2--; }
      tmp[b2 + 1] = key;
    }
    for (int q = 0; q < 9; q++) sn2[q] = tmp[q];
  }
  __syncthreads();
  if (t < HID) {
    float acc = l0b[t] + l1b[t] + l2b[t] + l3b[t] + l4b[t] + l5b[t];
    acc += x[i * 2 + 0] * l0w[t] + x[i * 2 + 1] * l0w[HID + t];
    for (int k = 0; k < KG; k++) acc += label[i * KG + k] * l1w[k * HID + t];
    for (int q = 0; q < AJR; q++) acc += sv[q] * l4w[q * HID + t];
    for (int q = 0; q < 9; q++) acc += sn2[q] * l5w[q * HID + t];
    base[i * HID + t] = acc;
  }
}

// ---------------------------------------------------------------------------
// B: one GCN step
// ---------------------------------------------------------------------------
__global__ __launch_bounds__(192) void k_gcn(
    const float* __restrict__ hin, const float* __restrict__ base,
    const float* __restrict__ w, const float* __restrict__ l2w,
    const float* __restrict__ l3w, float* __restrict__ hout) {
  int i = blockIdx.x; int t = threadIdx.x;
  int g = i / MG;
  __shared__ float n1[HID], n2[HID];
  if (t < HID) {
    float acc = 0.f, wsum = 0.f;
    for (int j = 0; j < DEG; j++) {
      int u = (j < i) ? j : j + 1;
      if (u / MG != g) {
        float wj = w[i * DEG + j];
        acc += wj * hin[u * HID + t];
        wsum += wj;
      }
    }
    n1[t] = acc / wsum;
  } else if (t < 2 * HID) {
    int dd = t - HID;
    float acc = 0.f, wsum = 0.f;
    for (int u = MG * g; u < MG * g + MG; u++) {
      if (u == i) continue;
      int j = (u < i) ? u : u - 1;
      float wj = w[i * DEG + j];
      acc += wj * hin[u * HID + dd];
      wsum += wj;
    }
    n2[dd] = acc / wsum;
  }
  __syncthreads();
  if (t < HID) {
    float acc = base[i * HID + t];
    for (int dd = 0; dd < HID; dd++)
      acc += n1[dd] * l2w[dd * HID + t] + n2[dd] * l3w[dd * HID + t];
    hout[i * HID + t] = fmaxf(acc, 0.f);
  }
}

// ---------------------------------------------------------------------------
// C1: h_full assembly (+ h, h_full outputs)
// ---------------------------------------------------------------------------
__global__ __launch_bounds__(128) void k_hfull(
    const float* __restrict__ h, const float* __restrict__ x,
    const float* __restrict__ label, const int* __restrict__ remain_step,
    float* __restrict__ hfull, float* __restrict__ out_h,
    float* __restrict__ out_hf) {
  int i = blockIdx.x; int t = threadIdx.x;
  if (t < HD) {
    float v;
    if (t < HID) {
      int p = *remain_step;
      int t2 = t & ~1;
      float div = expf(-(float)t2 * (logf(10000.f) / (float)HID));
      float ang = (float)p * div;
      float pe = (t & 1) ? cosf(ang) : sinf(ang);
      float hv = h[i * HID + t];
      out_h[i * HID + t] = hv;
      v = hv + pe;
    } else if (t < HID + 2) {
      v = x[i * 2 + (t - HID)];
    } else {
      v = label[i * KG + (t - HID - 2)];
    }
    hfull[i * HD + t] = v;
    out_hf[i * HD + t] = v;
  }
}

// C2: group means of h_full
__global__ __launch_bounds__(128) void k_gmean(
    const float* __restrict__ hfull, float* __restrict__ gmean) {
  int g = blockIdx.x; int t = threadIdx.x;
  if (t < HD) {
    float s = 0.f;
    for (int q = 0; q < MG; q++) s += hfull[(g * MG + q) * HD + t];
    gmean[g * HD + t] = s * 0.1f;
  }
}

// D1: sum of the 4 118-row blocks of mha_w{0,1}
__global__ __launch_bounds__(256) void k_wsum(
    const float* __restrict__ w0, const float* __restrict__ w1,
    float* __restrict__ W0s, float* __restrict__ W1s) {
  int idx = blockIdx.x * blockDim.x + threadIdx.x;
  if (idx < HD * DM) {
    int dp = idx / DM, c = idx - dp * DM;
    W0s[idx] = w0[dp * DM + c] + w0[(HD + dp) * DM + c] +
               w0[(2 * HD + dp) * DM + c] + w0[(3 * HD + dp) * DM + c];
    W1s[idx] = w1[dp * DM + c] + w1[(HD + dp) * DM + c] +
               w1[(2 * HD + dp) * DM + c] + w1[(3 * HD + dp) * DM + c];
  }
}

// D2: khf / vhf
__global__ __launch_bounds__(256) void k_kv(
    const float* __restrict__ hfull, const float* __restrict__ W0s,
    const float* __restrict__ b0v, const float* __restrict__ W1s,
    const float* __restrict__ b1v, float* __restrict__ khf,
    float* __restrict__ vhf) {
  int i = blockIdx.x; int t = threadIdx.x;
  __shared__ float hr[HD];
  if (t < HD) hr[t] = hfull[i * HD + t];
  __syncthreads();
  for (int c = t; c < DM; c += 256) {
    float a0 = b0v[c], a1 = b1v[c];
    for (int dd = 0; dd < HD; dd++) {
      float hv = hr[dd];
      a0 += hv * W0s[dd * DM + c];
      a1 += hv * W1s[dd * DM + c];
    }
    khf[i * DM + c] = a0;
    vhf[i * DM + c] = a1;
  }
}

// D3: B1/B2 (query decomposition)
__global__ __launch_bounds__(256) void k_B(
    const float* __restrict__ hfull, const float* __restrict__ gmean,
    const float* __restrict__ w0, const float* __restrict__ b0v,
    float* __restrict__ B1, float* __restrict__ B2) {
  int i = blockIdx.x; int t = threadIdx.x; int g = i / MG;
  __shared__ float hr[HD], gr[HD];
  if (t < HD) { hr[t] = hfull[i * HD + t]; gr[t] = gmean[g * HD + t]; }
  __syncthreads();
  for (int c = t; c < DM; c += 256) {
    float a1 = 0.f, a2 = b0v[c];
    for (int dd = 0; dd < HD; dd++) {
      a1 += hr[dd] * w0[dd * DM + c] + gr[dd] * w0[(2 * HD + dd) * DM + c];
      a2 += hr[dd] * w0[(HD + dd) * DM + c] + gr[dd] * w0[(3 * HD + dd) * DM + c];
    }
    B1[i * DM + c] = a1;
    B2[i * DM + c] = a2;
  }
}

// D4: score components SC1/SC2
__global__ __launch_bounds__(256) void k_SC(
    const float* __restrict__ B1, const float* __restrict__ B2,
    const float* __restrict__ khf, float* __restrict__ SC1,
    float* __restrict__ SC2) {
  int i = blockIdx.x; int t = threadIdx.x;
  __shared__ float b1r[DM], b2r[DM];
  for (int c = t; c < DM; c += 256) { b1r[c] = B1[i * DM + c]; b2r[c] = B2[i * DM + c]; }
  __syncthreads();
  for (int p = t; p < NH * NV; p += 256) {
    int h = p / NV, k = p - h * NV;
    float s1a = 0.f, s2a = 0.f;
    for (int dd = 0; dd < HD; dd++) {
      float kv = khf[k * DM + h * HD + dd];
      s1a += b1r[h * HD + dd] * kv;
      s2a += b2r[h * HD + dd] * kv;
    }
    SC1[h * NN + i * NV + k] = s1a;
    SC2[h * NN + i * NV + k] = s2a;
  }
}

// ---------------------------------------------------------------------------
// E: attention. O stored in bf16 now.
// ---------------------------------------------------------------------------
__global__ __launch_bounds__(256) void k_attn(
    const float* __restrict__ SC1, const float* __restrict__ SC2,
    const float* __restrict__ vhf, ushort* __restrict__ Ob) {
  int i = blockIdx.x, h = blockIdx.y, half = blockIdx.z;
  int d0 = half * 59;
  const int ND = 59;
  int t = threadIdx.x;
  __shared__ float vh_s[NV * 60];
  __shared__ float P[16 * NV];
  __shared__ float s1[NV];
  for (int e = t; e < NV * ND; e += 256) {
    int k = e / ND, dd = e - k * ND;
    vh_s[k * 60 + dd] = vhf[k * DM + h * HD + d0 + dd];
  }
  for (int k = t; k < NV; k += 256) s1[k] = SC1[h * NN + i * NV + k];
  __syncthreads();
  const float scale = 1.0f / sqrtf((float)HD);
  int tr = t >> 4, tl = t & 15;   // softmax: 16 rows x 16 lanes
  int tj = t >> 6, td = t & 63;   // PV: 4 row-groups x 64 dim lanes
  for (int jc = 0; jc < NV; jc += 16) {
    int rem = NV - jc; if (rem > 16) rem = 16;
    float m = -1e30f;
    if (tr < rem) {
      const float* sc2row = SC2 + h * NN + (jc + tr) * NV;
      for (int k = tl; k < NV; k += 16) {
        float s = (s1[k] + sc2row[k]) * scale;
        P[tr * NV + k] = s;
        m = fmaxf(m, s);
      }
    }
    m = fmaxf(m, __shfl_xor(m, 1));
    m = fmaxf(m, __shfl_xor(m, 2));
    m = fmaxf(m, __shfl_xor(m, 4));
    m = fmaxf(m, __shfl_xor(m, 8));
    float l = 0.f;
    if (tr < rem) {
      for (int k = tl; k < NV; k += 16) {
        float e = expf(P[tr * NV + k] - m);
        P[tr * NV + k] = e;
        l += e;
      }
    }
    l += __shfl_xor(l, 1); l += __shfl_xor(l, 2);
    l += __shfl_xor(l, 4); l += __shfl_xor(l, 8);
    if (tr < rem) {
      float rinv = 1.0f / l;
      for (int k = tl; k < NV; k += 16) P[tr * NV + k] *= rinv;
    }
    __syncthreads();
    if (td < ND) {
      float a0 = 0.f, a1 = 0.f, a2 = 0.f, a3 = 0.f;
      const float* P0 = P + (tj * 4 + 0) * NV;
      const float* P1 = P + (tj * 4 + 1) * NV;
      const float* P2 = P + (tj * 4 + 2) * NV;
      const float* P3 = P + (tj * 4 + 3) * NV;
      for (int k = 0; k < NV; k += 2) {
        float v0 = vh_s[k * 60 + td];
        float v1 = vh_s[(k + 1) * 60 + td];
        float2 p0 = *(const float2*)&P0[k];
        float2 p1 = *(const float2*)&P1[k];
        float2 p2 = *(const float2*)&P2[k];
        float2 p3 = *(const float2*)&P3[k];
        a0 += p0.x * v0 + p0.y * v1;
        a1 += p1.x * v0 + p1.y * v1;
        a2 += p2.x * v0 + p2.y * v1;
        a3 += p3.x * v0 + p3.y * v1;
      }
      float av[4] = {a0, a1, a2, a3};
      int bb = i * NV + jc;
      for (int rr = 0; rr < 4; rr++) {
        int r = tj * 4 + rr;
        if (r < rem)
          Ob[(size_t)(bb + r) * DM + h * HD + d0 + td] = f2bf(av[rr]);
      }
    }
    __syncthreads();
  }
}

// ---------------------------------------------------------------------------
// E2: w3T[c][k] = bf16(w3[k][c]), padded to [512][480] with zeros
// ---------------------------------------------------------------------------
__global__ __launch_bounds__(256) void k_w3T(
    const float* __restrict__ w3, ushort* __restrict__ w3T) {
  int idx = blockIdx.x * 256 + threadIdx.x;  // < 512*480 = 245760
  if (idx < 512 * 480) {
    int c = idx / 480, k = idx - c * 480;
    ushort v = 0;
    if (c < DM && k < DM) v = f2bf(w3[k * DM + c]);
    w3T[idx] = v;
  }
}

// ---------------------------------------------------------------------------
// E3: Osum[b] = Ob[b] + Ob[mirror(b)] (bf16 in/out, fp32 add)
// ---------------------------------------------------------------------------
__global__ __launch_bounds__(256) void k_osum(
    const ushort* __restrict__ Ob, ushort* __restrict__ Osum) {
  int e = blockIdx.x * 256 + threadIdx.x;  // e < NN*236 (ushort2 units)
  int b = e / 236, c2 = e - b * 236;
  int i = b / NV, j = b - i * NV;
  int mb = j * NV + i;
  uint u1 = ((const uint*)Ob)[e];
  uint u2 = ((const uint*)Ob)[(size_t)mb * 236 + c2];
  float lo = bf2f(u1 & 0xffffu) + bf2f(u2 & 0xffffu);
  float hi = bf2f(u1 >> 16) + bf2f(u2 >> 16);
  ((uint*)Osum)[e] = (uint)f2bf(lo) | ((uint)f2bf(hi) << 16);
}

// ---------------------------------------------------------------------------
// F: S = Osum @ w3 + 2*b3 via bf16 MFMA. 128x128 tile, K-steps of 32,
// 4 waves each computing 64x64 with 4x4 mfma_f32_16x16x32_bf16.
// LDS stride 40 bf16 (80B) breaks the 8-way conflict of a 64B stride.
// ---------------------------------------------------------------------------
__global__ __launch_bounds__(256) void k_sgemm(
    const ushort* __restrict__ Osum, const ushort* __restrict__ w3T,
    const float* __restrict__ b3, float* __restrict__ outS) {
  __shared__ __align__(16) ushort As[128 * 40];
  __shared__ __align__(16) ushort Bs[128 * 40];
  int t = threadIdx.x;
  int c0 = blockIdx.x * 128, b0 = blockIdx.y * 128;
  int r = t >> 1, kh = (t & 1) * 16;
  int lane = t & 63, wv = t >> 6;
  int wm = wv & 1, wn = wv >> 1;
  int frow = lane & 15, quad = lane >> 4;
  float4v acc[4][4];
#pragma unroll
  for (int m = 0; m < 4; m++)
#pragma unroll
    for (int n = 0; n < 4; n++) acc[m][n] = (float4v)(0.f);

  for (int step = 0; step < 15; ++step) {
    int k0 = step * 32;
    int gr = b0 + r, gk = k0 + kh;
    // B tile regs (w3T is padded — always safe)
    const uint4* wp = (const uint4*)(w3T + (size_t)(c0 + r) * 480 + gk);
    uint4 bq0 = wp[0], bq1 = wp[1];
    // A tile regs
    uint4 aq0, aq1;
    ushort atmp[16];
    bool fast = (gr < NN) && (gk + 16 <= DM);
    if (fast) {
      const uint4* op = (const uint4*)(Osum + (size_t)gr * DM + gk);
      aq0 = op[0]; aq1 = op[1];
    } else {
#pragma unroll
      for (int e = 0; e < 16; ++e) {
        int kk = gk + e;
        atmp[e] = (gr < NN && kk < DM) ? Osum[(size_t)gr * DM + kk] : (ushort)0;
      }
    }
    __syncthreads();
    if (fast) {
      *(uint4*)&As[r * 40 + kh] = aq0;
      *(uint4*)&As[r * 40 + kh + 8] = aq1;
    } else {
#pragma unroll
      for (int e = 0; e < 16; ++e) As[r * 40 + kh + e] = atmp[e];
    }
    *(uint4*)&Bs[r * 40 + kh] = bq0;
    *(uint4*)&Bs[r * 40 + kh + 8] = bq1;
    __syncthreads();
    short8v af[4], bf[4];
#pragma unroll
    for (int m = 0; m < 4; m++)
      af[m] = *(const short8v*)&As[(wm * 64 + m * 16 + frow) * 40 + quad * 8];
#pragma unroll
    for (int n = 0; n < 4; n++)
      bf[n] = *(const short8v*)&Bs[(wn * 64 + n * 16 + frow) * 40 + quad * 8];
#pragma unroll
    for (int m = 0; m < 4; m++)
#pragma unroll
      for (int n = 0; n < 4; n++)
        acc[m][n] = __builtin_amdgcn_mfma_f32_16x16x32_bf16(af[m], bf[n],
                                                            acc[m][n], 0, 0, 0);
  }
  // epilogue: C/D layout col=lane&15, row=quad*4+reg
  int col = lane & 15;
#pragma unroll
  for (int n = 0; n < 4; n++) {
    int c = c0 + wn * 64 + n * 16 + col;
    if (c >= DM) continue;
    float bb = 2.0f * b3[c];
#pragma unroll
    for (int m = 0; m < 4; m++) {
      int bbase = b0 + wm * 64 + m * 16 + quad * 4;
#pragma unroll
      for (int r2 = 0; r2 < 4; r2++) {
        int b = bbase + r2;
        if (b < NN) outS[(size_t)b * DM + c] = acc[m][n][r2] + bb;
      }
    }
  }
}

// ---------------------------------------------------------------------------
// G: Q_sa = relu(S@v1+b1)@v2 + b2
// ---------------------------------------------------------------------------
__global__ __launch_bounds__(256) void k_qsa(
    const float* __restrict__ S, const float* __restrict__ v1w,
    const float* __restrict__ v1b, const float* __restrict__ v2w,
    const float* __restrict__ v2b, float* __restrict__ outQ) {
  __shared__ float Ss[64][9];
  __shared__ float V1s[8][48];
  __shared__ float Ts[64][49];
  int t = threadIdx.x;
  int b0 = blockIdx.x * 64;
  int ty = t >> 4, tx = t & 15;
  int lr = t >> 2, lk = (t & 3) * 2;
  float acc[4][3];
#pragma unroll
  for (int y = 0; y < 4; y++)
#pragma unroll
    for (int xx = 0; xx < 3; xx++) acc[y][xx] = 0.f;
  for (int k0 = 0; k0 < DM; k0 += 8) {
    __syncthreads();
    Ss[lr][lk] = S[(size_t)(b0 + lr) * DM + k0 + lk];
    Ss[lr][lk + 1] = S[(size_t)(b0 + lr) * DM + k0 + lk + 1];
    if (t < 192) {
      int e = t * 2; int kk = e / 48, c = e - kk * 48;
      V1s[kk][c] = v1w[(k0 + kk) * 48 + c];
      V1s[kk][c + 1] = v1w[(k0 + kk) * 48 + c + 1];
    }
    __syncthreads();
#pragma unroll
    for (int kk = 0; kk < 8; kk++) {
      float a0 = Ss[ty * 4 + 0][kk], a1 = Ss[ty * 4 + 1][kk],
            a2 = Ss[ty * 4 + 2][kk], a3 = Ss[ty * 4 + 3][kk];
      float w0_ = V1s[kk][tx * 3 + 0], w1_ = V1s[kk][tx * 3 + 1],
            w2_ = V1s[kk][tx * 3 + 2];
      acc[0][0] += a0 * w0_; acc[0][1] += a0 * w1_; acc[0][2] += a0 * w2_;
      acc[1][0] += a1 * w0_; acc[1][1] += a1 * w1_; acc[1][2] += a1 * w2_;
      acc[2][0] += a2 * w0_; acc[2][1] += a2 * w1_; acc[2][2] += a2 * w2_;
      acc[3][0] += a3 * w0_; acc[3][1] += a3 * w1_; acc[3][2] += a3 * w2_;
    }
  }
#pragma unroll
  for (int y = 0; y < 4; y++)
#pragma unroll
    for (int xx = 0; xx < 3; xx++)
      Ts[ty * 4 + y][tx * 3 + xx] = fmaxf(acc[y][xx] + v1b[tx * 3 + xx], 0.f);
  __syncthreads();
  if (t < 64) {
    float q = v2b[0];
    for (int c = 0; c < 48; c++) q += Ts[t][c] * v2w[c];
    outQ[b0 + t] = q;
  }
}

// ---------------------------------------------------------------------------
extern "C" void kernel_launch(void* const* d_in, const int* in_sizes, int n_in,
                              void* d_out, int out_size, void* d_ws,
                              size_t ws_size, hipStream_t stream) {
  const float* x = (const float*)d_in[0];
  const float* label = (const float*)d_in[1];
  const float* h0 = (const float*)d_in[2];
  const float* w = (const float*)d_in[3];
  const float* dmat = (const float*)d_in[4];
  const float* l0w = (const float*)d_in[5];
  const float* l0b = (const float*)d_in[6];
  const float* l1w = (const float*)d_in[7];
  const float* l1b = (const float*)d_in[8];
  const float* l2w = (const float*)d_in[9];
  const float* l2b = (const float*)d_in[10];
  const float* l3w = (const float*)d_in[11];
  const float* l3b = (const float*)d_in[12];
  const float* l4w = (const float*)d_in[13];
  const float* l4b = (const float*)d_in[14];
  const float* l5w = (const float*)d_in[15];
  const float* l5b = (const float*)d_in[16];
  const float* w0 = (const float*)d_in[17];
  const float* b0v = (const float*)d_in[18];
  const float* w1 = (const float*)d_in[19];
  const float* b1v = (const float*)d_in[20];
  const float* w3 = (const float*)d_in[21];
  const float* b3 = (const float*)d_in[22];
  const float* v1w = (const float*)d_in[23];
  const float* v1b = (const float*)d_in[24];
  const float* v2w = (const float*)d_in[25];
  const float* v2b = (const float*)d_in[26];
  const int* remain_step = (const int*)d_in[29];

  float* ws = (float*)d_ws;
  float* base = ws + WS_BASE;
  float* h1 = ws + WS_H1;
  float* h2 = ws + WS_H2;
  float* hfull = ws + WS_HFULL;
  float* gmean = ws + WS_GMEAN;
  float* W0s = ws + WS_W0S;
  float* W1s = ws + WS_W1S;
  float* khf = ws + WS_KHF;
  float* vhf = ws + WS_VHF;
  float* B1 = ws + WS_B1;
  float* B2 = ws + WS_B2;
  float* SC1 = ws + WS_SC1;
  float* SC2 = ws + WS_SC2;
  ushort* Ob = (ushort*)(ws + WS_OB);
  ushort* Osum = (ushort*)(ws + WS_OSUM);
  ushort* w3T = (ushort*)(ws + WS_SC1);  // reuses SC1 slot after k_attn

  float* outS = (float*)d_out;
  float* outH = outS + OFF_H;
  float* outHF = outS + OFF_HF;
  float* outQ = outS + OFF_Q;

  k_base<<<NV, 256, 0, stream>>>(x, dmat, label, l0w, l0b, l1w, l1b, l2b, l3b,
                                 l4w, l4b, l5w, l5b, base);
  k_gcn<<<NV, 192, 0, stream>>>(h0, base, w, l2w, l3w, h1);
  k_gcn<<<NV, 192, 0, stream>>>(h1, base, w, l2w, l3w, h2);
  k_hfull<<<NV, 128, 0, stream>>>(h2, x, label, remain_step, hfull, outH, outHF);
  k_gmean<<<KG, 128, 0, stream>>>(hfull, gmean);
  k_wsum<<<(HD * DM + 255) / 256, 256, 0, stream>>>(w0, w1, W0s, W1s);
  k_kv<<<NV, 256, 0, stream>>>(hfull, W0s, b0v, W1s, b1v, khf, vhf);
  k_B<<<NV, 256, 0, stream>>>(hfull, gmean, w0, b0v, B1, B2);
  k_SC<<<NV, 256, 0, stream>>>(B1, B2, khf, SC1, SC2);
  k_attn<<<dim3(NV, NH, 2), 256, 0, stream>>>(SC1, SC2, vhf, Ob);
  k_w3T<<<960, 256, 0, stream>>>(w3, w3T);
  k_osum<<<(NN * 236) / 256, 256, 0, stream>>>(Ob, Osum);
  k_sgemm<<<dim3(4, 313), 256, 0, stream>>>(Osum, w3T, b3, outS);
  k_qsa<<<NN / 64, 256, 0, stream>>>(outS, v1w, v1b, v2w, v2b, outQ);
}

// Round 3
// 870.470 us; speedup vs baseline: 1.7239x; 1.1808x over previous
//
#include <hip/hip_runtime.h>
#include <hip/hip_bf16.h>
#include <math.h>

typedef unsigned short ushort;
typedef unsigned int uint;

// Sizes (fixed by the reference problem)
#define NV 200     // N nodes
#define DEG 199
#define HID 96
#define KG 20      // groups / one-hot width
#define MG 10      // group size
#define AJR 30
#define NH 4
#define HD 118     // HID + 2 + K
#define DM 472     // NH*HD
#define NN 40000   // N*N

// Workspace layout (float units). Total footprint = 19,772,552 floats = 79.1 MB
#define WS_BASE   0
#define WS_H1     19200
#define WS_H2     38400
#define WS_HFULL  57600
#define WS_GMEAN  81200
#define WS_W0S    83560   // after k_kv: reused for VB (B-frag vh, 57344 floats)
#define WS_W1S    139256
#define WS_KHF    194952
#define WS_VHF    289352
#define WS_B1     383752  // after k_SC: reused for C (softmax row consts, 160000 floats)
#define WS_B2     478152
#define WS_SC1    572552  // after k_attn2: reused for w3T (bf16)
#define WS_SC2    732552
#define WS_OB     892552   // O in bf16: 40000x472 ushort
#define WS_OSUM   10332552 // Osum bf16

// Output layout (floats)
#define OFF_H   18880000
#define OFF_HF  18899200
#define OFF_Q   18922800

typedef __attribute__((ext_vector_type(8))) short short8v;
typedef __attribute__((ext_vector_type(4))) float float4v;

__device__ __forceinline__ float bf2f(uint u) {
  return __uint_as_float(u << 16);
}
__device__ __forceinline__ ushort f2bf(float f) {
  uint u = __float_as_uint(f);
  uint r = (u + 0x7fffu + ((u >> 16) & 1u)) >> 16;  // RNE
  return (ushort)r;
}
__device__ __forceinline__ uint packbf(float a, float b) {
  __hip_bfloat162 h2 = __float22bfloat162_rn(make_float2(a, b));
  union { __hip_bfloat162 h; uint u; } c;
  c.h = h2;
  return c.u;
}

// ---------------------------------------------------------------------------
// A: iteration-invariant part of the GCN update
// ---------------------------------------------------------------------------
__global__ __launch_bounds__(256) void k_base(
    const float* __restrict__ x, const float* __restrict__ dmat,
    const float* __restrict__ label,
    const float* __restrict__ l0w, const float* __restrict__ l0b,
    const float* __restrict__ l1w, const float* __restrict__ l1b,
    const float* __restrict__ l2b, const float* __restrict__ l3b,
    const float* __restrict__ l4w, const float* __restrict__ l4b,
    const float* __restrict__ l5w, const float* __restrict__ l5b,
    float* __restrict__ base) {
  int i = blockIdx.x; int t = threadIdx.x;
  int g = i / MG;
  __shared__ float sv[256];
  __shared__ float sn2[9];
  float v = -1.0f;
  if (t < DEG) {
    int u = (t < i) ? t : t + 1;
    if (u / MG != g) v = dmat[i * DEG + t];
  }
  sv[t] = v;
  __syncthreads();
  for (int k2 = 2; k2 <= 256; k2 <<= 1) {
    for (int jj = k2 >> 1; jj > 0; jj >>= 1) {
      int ixj = t ^ jj;
      if (ixj > t) {
        float a = sv[t], b = sv[ixj];
        bool sw = ((t & k2) == 0) ? (a < b) : (a > b);
        if (sw) { sv[t] = b; sv[ixj] = a; }
      }
      __syncthreads();
    }
  }
  if (t == 0) {
    float tmp[9];
    for (int q = 0; q < 9; q++) tmp[q] = dmat[i * DEG + MG * g + q];
    for (int a2 = 1; a2 < 9; a2++) {
      float key = tmp[a2]; int b2 = a2 - 1;
      while (b2 >= 0 && tmp[b2] < key) { tmp[b2 + 1] = tmp[b2]; b2--; }
      tmp[b2 + 1] = key;
    }
    for (int q = 0; q < 9; q++) sn2[q] = tmp[q];
  }
  __syncthreads();
  if (t < HID) {
    float acc = l0b[t] + l1b[t] + l2b[t] + l3b[t] + l4b[t] + l5b[t];
    acc += x[i * 2 + 0] * l0w[t] + x[i * 2 + 1] * l0w[HID + t];
    for (int k = 0; k < KG; k++) acc += label[i * KG + k] * l1w[k * HID + t];
    for (int q = 0; q < AJR; q++) acc += sv[q] * l4w[q * HID + t];
    for (int q = 0; q < 9; q++) acc += sn2[q] * l5w[q * HID + t];
    base[i * HID + t] = acc;
  }
}

// ---------------------------------------------------------------------------
// B: one GCN step
// ---------------------------------------------------------------------------
__global__ __launch_bounds__(192) void k_gcn(
    const float* __restrict__ hin, const float* __restrict__ base,
    const float* __restrict__ w, const float* __restrict__ l2w,
    const float* __restrict__ l3w, float* __restrict__ hout) {
  int i = blockIdx.x; int t = threadIdx.x;
  int g = i / MG;
  __shared__ float n1[HID], n2[HID];
  if (t < HID) {
    float acc = 0.f, wsum = 0.f;
    for (int j = 0; j < DEG; j++) {
      int u = (j < i) ? j : j + 1;
      if (u / MG != g) {
        float wj = w[i * DEG + j];
        acc += wj * hin[u * HID + t];
        wsum += wj;
      }
    }
    n1[t] = acc / wsum;
  } else if (t < 2 * HID) {
    int dd = t - HID;
    float acc = 0.f, wsum = 0.f;
    for (int u = MG * g; u < MG * g + MG; u++) {
      if (u == i) continue;
      int j = (u < i) ? u : u - 1;
      float wj = w[i * DEG + j];
      acc += wj * hin[u * HID + dd];
      wsum += wj;
    }
    n2[dd] = acc / wsum;
  }
  __syncthreads();
  if (t < HID) {
    float acc = base[i * HID + t];
    for (int dd = 0; dd < HID; dd++)
      acc += n1[dd] * l2w[dd * HID + t] + n2[dd] * l3w[dd * HID + t];
    hout[i * HID + t] = fmaxf(acc, 0.f);
  }
}

// ---------------------------------------------------------------------------
// C1: h_full assembly (+ h, h_full outputs)
// ---------------------------------------------------------------------------
__global__ __launch_bounds__(128) void k_hfull(
    const float* __restrict__ h, const float* __restrict__ x,
    const float* __restrict__ label, const int* __restrict__ remain_step,
    float* __restrict__ hfull, float* __restrict__ out_h,
    float* __restrict__ out_hf) {
  int i = blockIdx.x; int t = threadIdx.x;
  if (t < HD) {
    float v;
    if (t < HID) {
      int p = *remain_step;
      int t2 = t & ~1;
      float div = expf(-(float)t2 * (logf(10000.f) / (float)HID));
      float ang = (float)p * div;
      float pe = (t & 1) ? cosf(ang) : sinf(ang);
      float hv = h[i * HID + t];
      out_h[i * HID + t] = hv;
      v = hv + pe;
    } else if (t < HID + 2) {
      v = x[i * 2 + (t - HID)];
    } else {
      v = label[i * KG + (t - HID - 2)];
    }
    hfull[i * HD + t] = v;
    out_hf[i * HD + t] = v;
  }
}

// C2: group means of h_full
__global__ __launch_bounds__(128) void k_gmean(
    const float* __restrict__ hfull, float* __restrict__ gmean) {
  int g = blockIdx.x; int t = threadIdx.x;
  if (t < HD) {
    float s = 0.f;
    for (int q = 0; q < MG; q++) s += hfull[(g * MG + q) * HD + t];
    gmean[g * HD + t] = s * 0.1f;
  }
}

// D1: sum of the 4 118-row blocks of mha_w{0,1}
__global__ __launch_bounds__(256) void k_wsum(
    const float* __restrict__ w0, const float* __restrict__ w1,
    float* __restrict__ W0s, float* __restrict__ W1s) {
  int idx = blockIdx.x * blockDim.x + threadIdx.x;
  if (idx < HD * DM) {
    int dp = idx / DM, c = idx - dp * DM;
    W0s[idx] = w0[dp * DM + c] + w0[(HD + dp) * DM + c] +
               w0[(2 * HD + dp) * DM + c] + w0[(3 * HD + dp) * DM + c];
    W1s[idx] = w1[dp * DM + c] + w1[(HD + dp) * DM + c] +
               w1[(2 * HD + dp) * DM + c] + w1[(3 * HD + dp) * DM + c];
  }
}

// D2: khf / vhf
__global__ __launch_bounds__(256) void k_kv(
    const float* __restrict__ hfull, const float* __restrict__ W0s,
    const float* __restrict__ b0v, const float* __restrict__ W1s,
    const float* __restrict__ b1v, float* __restrict__ khf,
    float* __restrict__ vhf) {
  int i = blockIdx.x; int t = threadIdx.x;
  __shared__ float hr[HD];
  if (t < HD) hr[t] = hfull[i * HD + t];
  __syncthreads();
  for (int c = t; c < DM; c += 256) {
    float a0 = b0v[c], a1 = b1v[c];
    for (int dd = 0; dd < HD; dd++) {
      float hv = hr[dd];
      a0 += hv * W0s[dd * DM + c];
      a1 += hv * W1s[dd * DM + c];
    }
    khf[i * DM + c] = a0;
    vhf[i * DM + c] = a1;
  }
}

// D2b: VB = vh in B-fragment layout, bf16. frag id f = (h*7+ks)*8+dt;
// element: lane holds B[k=ks*32+quad*8+q][n=dt*16+(lane&15)] (0-padded).
__global__ __launch_bounds__(256) void k_vhB(
    const float* __restrict__ vhf, ushort* __restrict__ VB) {
  int idx = blockIdx.x * 256 + threadIdx.x;
  if (idx >= NH * 7 * 8 * 64) return;
  int lane = idx & 63;
  int rest = idx >> 6;
  int dt = rest & 7;
  int hk = rest >> 3;
  int ks = hk % 7, h = hk / 7;
  int d = dt * 16 + (lane & 15);
  int kbase = ks * 32 + (lane >> 4) * 8;
  uint out[4];
#pragma unroll
  for (int p = 0; p < 4; ++p) {
    float a = 0.f, b = 0.f;
    int k0 = kbase + p * 2;
    if (d < HD) {
      if (k0 < NV) a = vhf[k0 * DM + h * HD + d];
      if (k0 + 1 < NV) b = vhf[(k0 + 1) * DM + h * HD + d];
    }
    out[p] = packbf(a, b);
  }
  *(uint4*)(VB + (size_t)idx * 8) = make_uint4(out[0], out[1], out[2], out[3]);
}

// D3: B1/B2 (query decomposition)
__global__ __launch_bounds__(256) void k_B(
    const float* __restrict__ hfull, const float* __restrict__ gmean,
    const float* __restrict__ w0, const float* __restrict__ b0v,
    float* __restrict__ B1, float* __restrict__ B2) {
  int i = blockIdx.x; int t = threadIdx.x; int g = i / MG;
  __shared__ float hr[HD], gr[HD];
  if (t < HD) { hr[t] = hfull[i * HD + t]; gr[t] = gmean[g * HD + t]; }
  __syncthreads();
  for (int c = t; c < DM; c += 256) {
    float a1 = 0.f, a2 = b0v[c];
    for (int dd = 0; dd < HD; dd++) {
      a1 += hr[dd] * w0[dd * DM + c] + gr[dd] * w0[(2 * HD + dd) * DM + c];
      a2 += hr[dd] * w0[(HD + dd) * DM + c] + gr[dd] * w0[(3 * HD + dd) * DM + c];
    }
    B1[i * DM + c] = a1;
    B2[i * DM + c] = a2;
  }
}

// D4: score components SC1/SC2, pre-scaled by (1/sqrt(HD))*log2(e)
__global__ __launch_bounds__(256) void k_SC(
    const float* __restrict__ B1, const float* __restrict__ B2,
    const float* __restrict__ khf, float* __restrict__ SC1,
    float* __restrict__ SC2) {
  int i = blockIdx.x; int t = threadIdx.x;
  const float scl = 1.4426950408889634f / sqrtf((float)HD);
  __shared__ float b1r[DM], b2r[DM];
  for (int c = t; c < DM; c += 256) { b1r[c] = B1[i * DM + c]; b2r[c] = B2[i * DM + c]; }
  __syncthreads();
  for (int p = t; p < NH * NV; p += 256) {
    int h = p / NV, k = p - h * NV;
    float s1a = 0.f, s2a = 0.f;
    for (int dd = 0; dd < HD; dd++) {
      float kv = khf[k * DM + h * HD + dd];
      s1a += b1r[h * HD + dd] * kv;
      s2a += b2r[h * HD + dd] * kv;
    }
    SC1[h * NN + i * NV + k] = s1a * scl;
    SC2[h * NN + i * NV + k] = s2a * scl;
  }
}

// D5: softmax row constants: C[h][i][j] = m + log2(l) in the exp2 domain
__global__ __launch_bounds__(256) void k_ml(
    const float* __restrict__ SC1, const float* __restrict__ SC2,
    float* __restrict__ C) {
  int i = blockIdx.x, h = blockIdx.y;
  int t = threadIdx.x;
  __shared__ float s1s[NV];
  for (int k = t; k < NV; k += 256) s1s[k] = SC1[h * NN + i * NV + k];
  __syncthreads();
  if (t < NV) {
    const float* s2p = SC2 + h * NN + t * NV;
    float m = -1e30f;
    for (int k = 0; k < NV; k++) m = fmaxf(m, s1s[k] + s2p[k]);
    float l = 0.f;
    for (int k = 0; k < NV; k++) l += exp2f(s1s[k] + s2p[k] - m);
    C[h * NN + i * NV + t] = m + log2f(l);
  }
}

// ---------------------------------------------------------------------------
// E: MFMA attention: O[(i,j)][h,d] = sum_k P * vh, with
// P = exp2(SC1''[h,i,k] + SC2''[h,j,k] - C[h,i,j]) generated in-register.
// Grid (i, h, j-half). Each wave: 1-2 j-tiles of 16 rows x 8 d-tiles x 7 k-steps.
// ---------------------------------------------------------------------------
__global__ __launch_bounds__(256) void k_attn2(
    const float* __restrict__ SC1, const float* __restrict__ SC2,
    const float* __restrict__ C, const ushort* __restrict__ VB,
    ushort* __restrict__ Ob) {
  int i = blockIdx.x, h = blockIdx.y, jh = blockIdx.z;
  int t = threadIdx.x;
  int lane = t & 63, wv = t >> 6;
  int m = lane & 15, quad = lane >> 4;
  __shared__ float s1s[224];
  __shared__ float Cs[112];
  for (int k = t; k < 224; k += 256)
    s1s[k] = (k < NV) ? SC1[h * NN + i * NV + k] : -1e30f;
  for (int r = t; r < 112; r += 256) {
    int rj = (r < 100) ? r : 99;
    Cs[r] = C[h * NN + i * NV + jh * 100 + rj];
  }
  __syncthreads();
  float4v acc[2][8];
#pragma unroll
  for (int s = 0; s < 2; s++)
#pragma unroll
    for (int d = 0; d < 8; d++) acc[s][d] = (float4v)(0.f);
  const float* s2base = SC2 + h * NN;
  int jmem[2]; float Crow[2]; int njt = 0;
#pragma unroll
  for (int sjt = 0; sjt < 2; sjt++) {
    int jt = wv + sjt * 4;
    if (jt < 7) {
      int jl = min(jt * 16 + m, 99);
      jmem[sjt] = jh * 100 + jl;
      Crow[sjt] = Cs[jl];
      njt = sjt + 1;
    }
  }
  for (int ks = 0; ks < 7; ++ks) {
    int kb = ks * 32 + quad * 8;
    short8v bfr[8];
#pragma unroll
    for (int dt = 0; dt < 8; ++dt)
      bfr[dt] = *(const short8v*)(VB +
          (size_t)((((h * 7 + ks) * 8 + dt) * 64 + lane)) * 8);
    for (int sjt = 0; sjt < njt; ++sjt) {
      union { uint4 q; short8v v; } af;
      if (kb < NV) {
        const float* s2p = s2base + jmem[sjt] * NV + kb;
        float4 sa = *(const float4*)(s2p);
        float4 sb = *(const float4*)(s2p + 4);
        float4 ta = *(const float4*)&s1s[kb];
        float4 tb = *(const float4*)&s1s[kb + 4];
        float cr = Crow[sjt];
        float p0 = exp2f(ta.x + sa.x - cr);
        float p1 = exp2f(ta.y + sa.y - cr);
        float p2 = exp2f(ta.z + sa.z - cr);
        float p3 = exp2f(ta.w + sa.w - cr);
        float p4 = exp2f(tb.x + sb.x - cr);
        float p5 = exp2f(tb.y + sb.y - cr);
        float p6 = exp2f(tb.z + sb.z - cr);
        float p7 = exp2f(tb.w + sb.w - cr);
        af.q.x = packbf(p0, p1);
        af.q.y = packbf(p2, p3);
        af.q.z = packbf(p4, p5);
        af.q.w = packbf(p6, p7);
      } else {
        af.q = make_uint4(0, 0, 0, 0);
      }
#pragma unroll
      for (int dt = 0; dt < 8; ++dt)
        acc[sjt][dt] = __builtin_amdgcn_mfma_f32_16x16x32_bf16(
            af.v, bfr[dt], acc[sjt][dt], 0, 0, 0);
    }
  }
  for (int sjt = 0; sjt < njt; ++sjt) {
    int jt = wv + sjt * 4;
#pragma unroll
    for (int r2 = 0; r2 < 4; ++r2) {
      int rl = jt * 16 + quad * 4 + r2;
      if (rl < 100) {
        int j = jh * 100 + rl;
        size_t rowb = (size_t)(i * NV + j) * DM + h * HD;
#pragma unroll
        for (int dt = 0; dt < 8; ++dt) {
          int d = dt * 16 + m;
          if (d < HD) Ob[rowb + d] = f2bf(acc[sjt][dt][r2]);
        }
      }
    }
  }
}

// ---------------------------------------------------------------------------
// E2: w3T[c][k] = bf16(w3[k][c]), padded to [512][480] with zeros
// ---------------------------------------------------------------------------
__global__ __launch_bounds__(256) void k_w3T(
    const float* __restrict__ w3, ushort* __restrict__ w3T) {
  int idx = blockIdx.x * 256 + threadIdx.x;
  if (idx < 512 * 480) {
    int c = idx / 480, k = idx - c * 480;
    ushort v = 0;
    if (c < DM && k < DM) v = f2bf(w3[k * DM + c]);
    w3T[idx] = v;
  }
}

// ---------------------------------------------------------------------------
// E3: Osum[b] = Ob[b] + Ob[mirror(b)]
// ---------------------------------------------------------------------------
__global__ __launch_bounds__(256) void k_osum(
    const ushort* __restrict__ Ob, ushort* __restrict__ Osum) {
  int e = blockIdx.x * 256 + threadIdx.x;
  int b = e / 236, c2 = e - b * 236;
  int i = b / NV, j = b - i * NV;
  int mb = j * NV + i;
  uint u1 = ((const uint*)Ob)[e];
  uint u2 = ((const uint*)Ob)[(size_t)mb * 236 + c2];
  float lo = bf2f(u1 & 0xffffu) + bf2f(u2 & 0xffffu);
  float hi = bf2f(u1 >> 16) + bf2f(u2 >> 16);
  ((uint*)Osum)[e] = (uint)f2bf(lo) | ((uint)f2bf(hi) << 16);
}

// ---------------------------------------------------------------------------
// F: S = Osum @ w3 + 2*b3 via bf16 MFMA. 128x128 tile, K-steps of 32.
// ---------------------------------------------------------------------------
__global__ __launch_bounds__(256) void k_sgemm(
    const ushort* __restrict__ Osum, const ushort* __restrict__ w3T,
    const float* __restrict__ b3, float* __restrict__ outS) {
  __shared__ __align__(16) ushort As[128 * 40];
  __shared__ __align__(16) ushort Bs[128 * 40];
  int t = threadIdx.x;
  int c0 = blockIdx.x * 128, b0 = blockIdx.y * 128;
  int r = t >> 1, kh = (t & 1) * 16;
  int lane = t & 63, wv = t >> 6;
  int wm = wv & 1, wn = wv >> 1;
  int frow = lane & 15, quad = lane >> 4;
  float4v acc[4][4];
#pragma unroll
  for (int m = 0; m < 4; m++)
#pragma unroll
    for (int n = 0; n < 4; n++) acc[m][n] = (float4v)(0.f);

  for (int step = 0; step < 15; ++step) {
    int k0 = step * 32;
    int gr = b0 + r, gk = k0 + kh;
    const uint4* wp = (const uint4*)(w3T + (size_t)(c0 + r) * 480 + gk);
    uint4 bq0 = wp[0], bq1 = wp[1];
    uint4 aq0, aq1;
    ushort atmp[16];
    bool fast = (gr < NN) && (gk + 16 <= DM);
    if (fast) {
      const uint4* op = (const uint4*)(Osum + (size_t)gr * DM + gk);
      aq0 = op[0]; aq1 = op[1];
    } else {
#pragma unroll
      for (int e = 0; e < 16; ++e) {
        int kk = gk + e;
        atmp[e] = (gr < NN && kk < DM) ? Osum[(size_t)gr * DM + kk] : (ushort)0;
      }
    }
    __syncthreads();
    if (fast) {
      *(uint4*)&As[r * 40 + kh] = aq0;
      *(uint4*)&As[r * 40 + kh + 8] = aq1;
    } else {
#pragma unroll
      for (int e = 0; e < 16; ++e) As[r * 40 + kh + e] = atmp[e];
    }
    *(uint4*)&Bs[r * 40 + kh] = bq0;
    *(uint4*)&Bs[r * 40 + kh + 8] = bq1;
    __syncthreads();
    short8v af[4], bf[4];
#pragma unroll
    for (int m = 0; m < 4; m++)
      af[m] = *(const short8v*)&As[(wm * 64 + m * 16 + frow) * 40 + quad * 8];
#pragma unroll
    for (int n = 0; n < 4; n++)
      bf[n] = *(const short8v*)&Bs[(wn * 64 + n * 16 + frow) * 40 + quad * 8];
#pragma unroll
    for (int m = 0; m < 4; m++)
#pragma unroll
      for (int n = 0; n < 4; n++)
        acc[m][n] = __builtin_amdgcn_mfma_f32_16x16x32_bf16(af[m], bf[n],
                                                            acc[m][n], 0, 0, 0);
  }
  int col = lane & 15;
#pragma unroll
  for (int n = 0; n < 4; n++) {
    int c = c0 + wn * 64 + n * 16 + col;
    if (c >= DM) continue;
    float bb = 2.0f * b3[c];
#pragma unroll
    for (int m = 0; m < 4; m++) {
      int bbase = b0 + wm * 64 + m * 16 + quad * 4;
#pragma unroll
      for (int r2 = 0; r2 < 4; r2++) {
        int b = bbase + r2;
        if (b < NN) outS[(size_t)b * DM + c] = acc[m][n][r2] + bb;
      }
    }
  }
}

// ---------------------------------------------------------------------------
// G: Q_sa = relu(S@v1+b1)@v2 + b2
// ---------------------------------------------------------------------------
__global__ __launch_bounds__(256) void k_qsa(
    const float* __restrict__ S, const float* __restrict__ v1w,
    const float* __restrict__ v1b, const float* __restrict__ v2w,
    const float* __restrict__ v2b, float* __restrict__ outQ) {
  __shared__ float Ss[64][9];
  __shared__ float V1s[8][48];
  __shared__ float Ts[64][49];
  int t = threadIdx.x;
  int b0 = blockIdx.x * 64;
  int ty = t >> 4, tx = t & 15;
  int lr = t >> 2, lk = (t & 3) * 2;
  float acc[4][3];
#pragma unroll
  for (int y = 0; y < 4; y++)
#pragma unroll
    for (int xx = 0; xx < 3; xx++) acc[y][xx] = 0.f;
  for (int k0 = 0; k0 < DM; k0 += 8) {
    __syncthreads();
    Ss[lr][lk] = S[(size_t)(b0 + lr) * DM + k0 + lk];
    Ss[lr][lk + 1] = S[(size_t)(b0 + lr) * DM + k0 + lk + 1];
    if (t < 192) {
      int e = t * 2; int kk = e / 48, c = e - kk * 48;
      V1s[kk][c] = v1w[(k0 + kk) * 48 + c];
      V1s[kk][c + 1] = v1w[(k0 + kk) * 48 + c + 1];
    }
    __syncthreads();
#pragma unroll
    for (int kk = 0; kk < 8; kk++) {
      float a0 = Ss[ty * 4 + 0][kk], a1 = Ss[ty * 4 + 1][kk],
            a2 = Ss[ty * 4 + 2][kk], a3 = Ss[ty * 4 + 3][kk];
      float w0_ = V1s[kk][tx * 3 + 0], w1_ = V1s[kk][tx * 3 + 1],
            w2_ = V1s[kk][tx * 3 + 2];
      acc[0][0] += a0 * w0_; acc[0][1] += a0 * w1_; acc[0][2] += a0 * w2_;
      acc[1][0] += a1 * w0_; acc[1][1] += a1 * w1_; acc[1][2] += a1 * w2_;
      acc[2][0] += a2 * w0_; acc[2][1] += a2 * w1_; acc[2][2] += a2 * w2_;
      acc[3][0] += a3 * w0_; acc[3][1] += a3 * w1_; acc[3][2] += a3 * w2_;
    }
  }
#pragma unroll
  for (int y = 0; y < 4; y++)
#pragma unroll
    for (int xx = 0; xx < 3; xx++)
      Ts[ty * 4 + y][tx * 3 + xx] = fmaxf(acc[y][xx] + v1b[tx * 3 + xx], 0.f);
  __syncthreads();
  if (t < 64) {
    float q = v2b[0];
    for (int c = 0; c < 48; c++) q += Ts[t][c] * v2w[c];
    outQ[b0 + t] = q;
  }
}

// ---------------------------------------------------------------------------
extern "C" void kernel_launch(void* const* d_in, const int* in_sizes, int n_in,
                              void* d_out, int out_size, void* d_ws,
                              size_t ws_size, hipStream_t stream) {
  const float* x = (const float*)d_in[0];
  const float* label = (const float*)d_in[1];
  const float* h0 = (const float*)d_in[2];
  const float* w = (const float*)d_in[3];
  const float* dmat = (const float*)d_in[4];
  const float* l0w = (const float*)d_in[5];
  const float* l0b = (const float*)d_in[6];
  const float* l1w = (const float*)d_in[7];
  const float* l1b = (const float*)d_in[8];
  const float* l2w = (const float*)d_in[9];
  const float* l2b = (const float*)d_in[10];
  const float* l3w = (const float*)d_in[11];
  const float* l3b = (const float*)d_in[12];
  const float* l4w = (const float*)d_in[13];
  const float* l4b = (const float*)d_in[14];
  const float* l5w = (const float*)d_in[15];
  const float* l5b = (const float*)d_in[16];
  const float* w0 = (const float*)d_in[17];
  const float* b0v = (const float*)d_in[18];
  const float* w1 = (const float*)d_in[19];
  const float* b1v = (const float*)d_in[20];
  const float* w3 = (const float*)d_in[21];
  const float* b3 = (const float*)d_in[22];
  const float* v1w = (const float*)d_in[23];
  const float* v1b = (const float*)d_in[24];
  const float* v2w = (const float*)d_in[25];
  const float* v2b = (const float*)d_in[26];
  const int* remain_step = (const int*)d_in[29];

  float* ws = (float*)d_ws;
  float* base = ws + WS_BASE;
  float* h1 = ws + WS_H1;
  float* h2 = ws + WS_H2;
  float* hfull = ws + WS_HFULL;
  float* gmean = ws + WS_GMEAN;
  float* W0s = ws + WS_W0S;
  float* W1s = ws + WS_W1S;
  float* khf = ws + WS_KHF;
  float* vhf = ws + WS_VHF;
  float* B1 = ws + WS_B1;
  float* B2 = ws + WS_B2;
  float* SC1 = ws + WS_SC1;
  float* SC2 = ws + WS_SC2;
  ushort* Ob = (ushort*)(ws + WS_OB);
  ushort* Osum = (ushort*)(ws + WS_OSUM);
  ushort* w3T = (ushort*)(ws + WS_SC1);   // reuses SC1 slot after k_attn2
  ushort* VB = (ushort*)(ws + WS_W0S);    // reuses W0s/W1s slots after k_kv
  float* C = ws + WS_B1;                  // reuses B1/B2 slots after k_SC

  float* outS = (float*)d_out;
  float* outH = outS + OFF_H;
  float* outHF = outS + OFF_HF;
  float* outQ = outS + OFF_Q;

  k_base<<<NV, 256, 0, stream>>>(x, dmat, label, l0w, l0b, l1w, l1b, l2b, l3b,
                                 l4w, l4b, l5w, l5b, base);
  k_gcn<<<NV, 192, 0, stream>>>(h0, base, w, l2w, l3w, h1);
  k_gcn<<<NV, 192, 0, stream>>>(h1, base, w, l2w, l3w, h2);
  k_hfull<<<NV, 128, 0, stream>>>(h2, x, label, remain_step, hfull, outH, outHF);
  k_gmean<<<KG, 128, 0, stream>>>(hfull, gmean);
  k_wsum<<<(HD * DM + 255) / 256, 256, 0, stream>>>(w0, w1, W0s, W1s);
  k_kv<<<NV, 256, 0, stream>>>(hfull, W0s, b0v, W1s, b1v, khf, vhf);
  k_vhB<<<(NH * 7 * 8 * 64 + 255) / 256, 256, 0, stream>>>(vhf, VB);
  k_B<<<NV, 256, 0, stream>>>(hfull, gmean, w0, b0v, B1, B2);
  k_SC<<<NV, 256, 0, stream>>>(B1, B2, khf, SC1, SC2);
  k_ml<<<dim3(NV, NH), 256, 0, stream>>>(SC1, SC2, C);
  k_attn2<<<dim3(NV, NH, 2), 256, 0, stream>>>(SC1, SC2, C, VB, Ob);
  k_w3T<<<960, 256, 0, stream>>>(w3, w3T);
  k_osum<<<(NN * 236) / 256, 256, 0, stream>>>(Ob, Osum);
  k_sgemm<<<dim3(4, 313), 256, 0, stream>>>(Osum, w3T, b3, outS);
  k_qsa<<<NN / 64, 256, 0, stream>>>(outS, v1w, v1b, v2w, v2b, outQ);
}

// Round 4
// 786.497 us; speedup vs baseline: 1.9080x; 1.1068x over previous
//
#include <hip/hip_runtime.h>
#include <hip/hip_bf16.h>
#include <math.h>

typedef unsigned short ushort;
typedef unsigned int uint;

// Sizes (fixed by the reference problem)
#define NV 200     // N nodes
#define DEG 199
#define HID 96
#define KG 20      // groups / one-hot width
#define MG 10      // group size
#define AJR 30
#define NH 4
#define HD 118     // HID + 2 + K
#define DM 472     // NH*HD
#define NN 40000   // N*N

// Workspace layout (float units). Max footprint now 11,132,552 floats = 44.5 MB.
#define WS_BASE   0
#define WS_H1     19200
#define WS_H2     38400
#define WS_HFULL  57600
#define WS_GMEAN  81200
#define WS_W0S    83560   // after k_kv: reused for VB (B-frag vh, bf16)
#define WS_W1S    139256
#define WS_KHF    194952
#define WS_VHF    289352
#define WS_B1     383752  // after k_SC: reused for C (softmax row consts, 160000 floats)
#define WS_B2     478152
#define WS_SC1    572552  // after k_attn2: reused for w3T (512x512 bf16 = 131072 floats)
#define WS_SC2    732552
#define WS_OT     892552  // OT[h][i][j][128] bf16 = 20,480,000 ushorts = 10,240,000 floats

// Output layout (floats)
#define OFF_H   18880000
#define OFF_HF  18899200
#define OFF_Q   18922800

typedef __attribute__((ext_vector_type(8))) short short8v;
typedef __attribute__((ext_vector_type(4))) float float4v;

__device__ __forceinline__ float bf2f(uint u) {
  return __uint_as_float(u << 16);
}
__device__ __forceinline__ ushort f2bf(float f) {
  uint u = __float_as_uint(f);
  uint r = (u + 0x7fffu + ((u >> 16) & 1u)) >> 16;  // RNE
  return (ushort)r;
}
__device__ __forceinline__ uint packbf(float a, float b) {
  __hip_bfloat162 h2 = __float22bfloat162_rn(make_float2(a, b));
  union { __hip_bfloat162 h; uint u; } c;
  c.h = h2;
  return c.u;
}
// bf16x2 + bf16x2 (fp32 math, RNE repack)
__device__ __forceinline__ uint addbf2(uint a, uint b) {
  float lo = bf2f(a & 0xffffu) + bf2f(b & 0xffffu);
  float hi = bf2f(a >> 16) + bf2f(b >> 16);
  return packbf(lo, hi);
}

// ---------------------------------------------------------------------------
// A: iteration-invariant part of the GCN update
// ---------------------------------------------------------------------------
__global__ __launch_bounds__(256) void k_base(
    const float* __restrict__ x, const float* __restrict__ dmat,
    const float* __restrict__ label,
    const float* __restrict__ l0w, const float* __restrict__ l0b,
    const float* __restrict__ l1w, const float* __restrict__ l1b,
    const float* __restrict__ l2b, const float* __restrict__ l3b,
    const float* __restrict__ l4w, const float* __restrict__ l4b,
    const float* __restrict__ l5w, const float* __restrict__ l5b,
    float* __restrict__ base) {
  int i = blockIdx.x; int t = threadIdx.x;
  int g = i / MG;
  __shared__ float sv[256];
  __shared__ float sn2[9];
  float v = -1.0f;
  if (t < DEG) {
    int u = (t < i) ? t : t + 1;
    if (u / MG != g) v = dmat[i * DEG + t];
  }
  sv[t] = v;
  __syncthreads();
  for (int k2 = 2; k2 <= 256; k2 <<= 1) {
    for (int jj = k2 >> 1; jj > 0; jj >>= 1) {
      int ixj = t ^ jj;
      if (ixj > t) {
        float a = sv[t], b = sv[ixj];
        bool sw = ((t & k2) == 0) ? (a < b) : (a > b);
        if (sw) { sv[t] = b; sv[ixj] = a; }
      }
      __syncthreads();
    }
  }
  if (t == 0) {
    float tmp[9];
    for (int q = 0; q < 9; q++) tmp[q] = dmat[i * DEG + MG * g + q];
    for (int a2 = 1; a2 < 9; a2++) {
      float key = tmp[a2]; int b2 = a2 - 1;
      while (b2 >= 0 && tmp[b2] < key) { tmp[b2 + 1] = tmp[b2]; b2--; }
      tmp[b2 + 1] = key;
    }
    for (int q = 0; q < 9; q++) sn2[q] = tmp[q];
  }
  __syncthreads();
  if (t < HID) {
    float acc = l0b[t] + l1b[t] + l2b[t] + l3b[t] + l4b[t] + l5b[t];
    acc += x[i * 2 + 0] * l0w[t] + x[i * 2 + 1] * l0w[HID + t];
    for (int k = 0; k < KG; k++) acc += label[i * KG + k] * l1w[k * HID + t];
    for (int q = 0; q < AJR; q++) acc += sv[q] * l4w[q * HID + t];
    for (int q = 0; q < 9; q++) acc += sn2[q] * l5w[q * HID + t];
    base[i * HID + t] = acc;
  }
}

// ---------------------------------------------------------------------------
// B: one GCN step
// ---------------------------------------------------------------------------
__global__ __launch_bounds__(192) void k_gcn(
    const float* __restrict__ hin, const float* __restrict__ base,
    const float* __restrict__ w, const float* __restrict__ l2w,
    const float* __restrict__ l3w, float* __restrict__ hout) {
  int i = blockIdx.x; int t = threadIdx.x;
  int g = i / MG;
  __shared__ float n1[HID], n2[HID];
  if (t < HID) {
    float acc = 0.f, wsum = 0.f;
    for (int j = 0; j < DEG; j++) {
      int u = (j < i) ? j : j + 1;
      if (u / MG != g) {
        float wj = w[i * DEG + j];
        acc += wj * hin[u * HID + t];
        wsum += wj;
      }
    }
    n1[t] = acc / wsum;
  } else if (t < 2 * HID) {
    int dd = t - HID;
    float acc = 0.f, wsum = 0.f;
    for (int u = MG * g; u < MG * g + MG; u++) {
      if (u == i) continue;
      int j = (u < i) ? u : u - 1;
      float wj = w[i * DEG + j];
      acc += wj * hin[u * HID + dd];
      wsum += wj;
    }
    n2[dd] = acc / wsum;
  }
  __syncthreads();
  if (t < HID) {
    float acc = base[i * HID + t];
    for (int dd = 0; dd < HID; dd++)
      acc += n1[dd] * l2w[dd * HID + t] + n2[dd] * l3w[dd * HID + t];
    hout[i * HID + t] = fmaxf(acc, 0.f);
  }
}

// ---------------------------------------------------------------------------
// C1: h_full assembly (+ h, h_full outputs)
// ---------------------------------------------------------------------------
__global__ __launch_bounds__(128) void k_hfull(
    const float* __restrict__ h, const float* __restrict__ x,
    const float* __restrict__ label, const int* __restrict__ remain_step,
    float* __restrict__ hfull, float* __restrict__ out_h,
    float* __restrict__ out_hf) {
  int i = blockIdx.x; int t = threadIdx.x;
  if (t < HD) {
    float v;
    if (t < HID) {
      int p = *remain_step;
      int t2 = t & ~1;
      float div = expf(-(float)t2 * (logf(10000.f) / (float)HID));
      float ang = (float)p * div;
      float pe = (t & 1) ? cosf(ang) : sinf(ang);
      float hv = h[i * HID + t];
      out_h[i * HID + t] = hv;
      v = hv + pe;
    } else if (t < HID + 2) {
      v = x[i * 2 + (t - HID)];
    } else {
      v = label[i * KG + (t - HID - 2)];
    }
    hfull[i * HD + t] = v;
    out_hf[i * HD + t] = v;
  }
}

// C2: group means of h_full
__global__ __launch_bounds__(128) void k_gmean(
    const float* __restrict__ hfull, float* __restrict__ gmean) {
  int g = blockIdx.x; int t = threadIdx.x;
  if (t < HD) {
    float s = 0.f;
    for (int q = 0; q < MG; q++) s += hfull[(g * MG + q) * HD + t];
    gmean[g * HD + t] = s * 0.1f;
  }
}

// D1: sum of the 4 118-row blocks of mha_w{0,1}
__global__ __launch_bounds__(256) void k_wsum(
    const float* __restrict__ w0, const float* __restrict__ w1,
    float* __restrict__ W0s, float* __restrict__ W1s) {
  int idx = blockIdx.x * blockDim.x + threadIdx.x;
  if (idx < HD * DM) {
    int dp = idx / DM, c = idx - dp * DM;
    W0s[idx] = w0[dp * DM + c] + w0[(HD + dp) * DM + c] +
               w0[(2 * HD + dp) * DM + c] + w0[(3 * HD + dp) * DM + c];
    W1s[idx] = w1[dp * DM + c] + w1[(HD + dp) * DM + c] +
               w1[(2 * HD + dp) * DM + c] + w1[(3 * HD + dp) * DM + c];
  }
}

// D2: khf / vhf
__global__ __launch_bounds__(256) void k_kv(
    const float* __restrict__ hfull, const float* __restrict__ W0s,
    const float* __restrict__ b0v, const float* __restrict__ W1s,
    const float* __restrict__ b1v, float* __restrict__ khf,
    float* __restrict__ vhf) {
  int i = blockIdx.x; int t = threadIdx.x;
  __shared__ float hr[HD];
  if (t < HD) hr[t] = hfull[i * HD + t];
  __syncthreads();
  for (int c = t; c < DM; c += 256) {
    float a0 = b0v[c], a1 = b1v[c];
    for (int dd = 0; dd < HD; dd++) {
      float hv = hr[dd];
      a0 += hv * W0s[dd * DM + c];
      a1 += hv * W1s[dd * DM + c];
    }
    khf[i * DM + c] = a0;
    vhf[i * DM + c] = a1;
  }
}

// D2b: VB = vh in B-fragment layout, bf16 (zero-padded d>=HD, k>=NV)
__global__ __launch_bounds__(256) void k_vhB(
    const float* __restrict__ vhf, ushort* __restrict__ VB) {
  int idx = blockIdx.x * 256 + threadIdx.x;
  if (idx >= NH * 7 * 8 * 64) return;
  int lane = idx & 63;
  int rest = idx >> 6;
  int dt = rest & 7;
  int hk = rest >> 3;
  int ks = hk % 7, h = hk / 7;
  int d = dt * 16 + (lane & 15);
  int kbase = ks * 32 + (lane >> 4) * 8;
  uint out[4];
#pragma unroll
  for (int p = 0; p < 4; ++p) {
    float a = 0.f, b = 0.f;
    int k0 = kbase + p * 2;
    if (d < HD) {
      if (k0 < NV) a = vhf[k0 * DM + h * HD + d];
      if (k0 + 1 < NV) b = vhf[(k0 + 1) * DM + h * HD + d];
    }
    out[p] = packbf(a, b);
  }
  *(uint4*)(VB + (size_t)idx * 8) = make_uint4(out[0], out[1], out[2], out[3]);
}

// D3: B1/B2 (query decomposition)
__global__ __launch_bounds__(256) void k_B(
    const float* __restrict__ hfull, const float* __restrict__ gmean,
    const float* __restrict__ w0, const float* __restrict__ b0v,
    float* __restrict__ B1, float* __restrict__ B2) {
  int i = blockIdx.x; int t = threadIdx.x; int g = i / MG;
  __shared__ float hr[HD], gr[HD];
  if (t < HD) { hr[t] = hfull[i * HD + t]; gr[t] = gmean[g * HD + t]; }
  __syncthreads();
  for (int c = t; c < DM; c += 256) {
    float a1 = 0.f, a2 = b0v[c];
    for (int dd = 0; dd < HD; dd++) {
      a1 += hr[dd] * w0[dd * DM + c] + gr[dd] * w0[(2 * HD + dd) * DM + c];
      a2 += hr[dd] * w0[(HD + dd) * DM + c] + gr[dd] * w0[(3 * HD + dd) * DM + c];
    }
    B1[i * DM + c] = a1;
    B2[i * DM + c] = a2;
  }
}

// D4: score components SC1/SC2, pre-scaled by (1/sqrt(HD))*log2(e)
__global__ __launch_bounds__(256) void k_SC(
    const float* __restrict__ B1, const float* __restrict__ B2,
    const float* __restrict__ khf, float* __restrict__ SC1,
    float* __restrict__ SC2) {
  int i = blockIdx.x; int t = threadIdx.x;
  const float scl = 1.4426950408889634f / sqrtf((float)HD);
  __shared__ float b1r[DM], b2r[DM];
  for (int c = t; c < DM; c += 256) { b1r[c] = B1[i * DM + c]; b2r[c] = B2[i * DM + c]; }
  __syncthreads();
  for (int p = t; p < NH * NV; p += 256) {
    int h = p / NV, k = p - h * NV;
    float s1a = 0.f, s2a = 0.f;
    for (int dd = 0; dd < HD; dd++) {
      float kv = khf[k * DM + h * HD + dd];
      s1a += b1r[h * HD + dd] * kv;
      s2a += b2r[h * HD + dd] * kv;
    }
    SC1[h * NN + i * NV + k] = s1a * scl;
    SC2[h * NN + i * NV + k] = s2a * scl;
  }
}

// D5: softmax row constants C[h][i][j] = m + log2(l), coalesced row scans.
// 8 half-wave groups per block; each group scans whole SC2 rows (128B/access).
__global__ __launch_bounds__(256) void k_ml(
    const float* __restrict__ SC1, const float* __restrict__ SC2,
    float* __restrict__ C) {
  int i = blockIdx.x, h = blockIdx.y;
  int t = threadIdx.x;
  __shared__ float s1s[224];
  for (int k = t; k < 224; k += 256)
    s1s[k] = (k < NV) ? SC1[h * NN + i * NV + k] : -1e30f;
  __syncthreads();
  int l = t & 31;   // lane within group
  int g = t >> 5;   // group 0..7
  const float* s2b = SC2 + h * NN;
  for (int it = 0; it < 25; ++it) {
    int j = it * 8 + g;
    const float* row = s2b + j * NV;
    float v[7];
#pragma unroll
    for (int e = 0; e < 7; ++e) {
      int k = l + 32 * e;
      v[e] = (k < NV) ? (s1s[k] + row[k]) : -1e30f;
    }
    float m = v[0];
#pragma unroll
    for (int e = 1; e < 7; ++e) m = fmaxf(m, v[e]);
#pragma unroll
    for (int off = 16; off > 0; off >>= 1) m = fmaxf(m, __shfl_xor(m, off, 32));
    float s = 0.f;
#pragma unroll
    for (int e = 0; e < 7; ++e) s += exp2f(v[e] - m);
#pragma unroll
    for (int off = 16; off > 0; off >>= 1) s += __shfl_xor(s, off, 32);
    if (l == 0) C[h * NN + i * NV + j] = m + log2f(s);
  }
}

// ---------------------------------------------------------------------------
// E: MFMA attention -> OT[h][i][j][128] (padded rows = two full 128B lines,
// exclusively owned and fully written by one block: no partial-line RMW).
// ---------------------------------------------------------------------------
__global__ __launch_bounds__(256) void k_attn2(
    const float* __restrict__ SC1, const float* __restrict__ SC2,
    const float* __restrict__ C, const ushort* __restrict__ VB,
    ushort* __restrict__ OT) {
  int i = blockIdx.x, h = blockIdx.y, jh = blockIdx.z;
  int t = threadIdx.x;
  int lane = t & 63, wv = t >> 6;
  int m = lane & 15, quad = lane >> 4;
  __shared__ float s1s[224];
  __shared__ float Cs[112];
  for (int k = t; k < 224; k += 256)
    s1s[k] = (k < NV) ? SC1[h * NN + i * NV + k] : -1e30f;
  for (int r = t; r < 112; r += 256) {
    int rj = (r < 100) ? r : 99;
    Cs[r] = C[h * NN + i * NV + jh * 100 + rj];
  }
  __syncthreads();
  float4v acc[2][8];
#pragma unroll
  for (int s = 0; s < 2; s++)
#pragma unroll
    for (int d = 0; d < 8; d++) acc[s][d] = (float4v)(0.f);
  const float* s2base = SC2 + h * NN;
  int jmem[2]; float Crow[2]; int njt = 0;
#pragma unroll
  for (int sjt = 0; sjt < 2; sjt++) {
    int jt = wv + sjt * 4;
    if (jt < 7) {
      int jl = min(jt * 16 + m, 99);
      jmem[sjt] = jh * 100 + jl;
      Crow[sjt] = Cs[jl];
      njt = sjt + 1;
    }
  }
  for (int ks = 0; ks < 7; ++ks) {
    int kb = ks * 32 + quad * 8;
    short8v bfr[8];
#pragma unroll
    for (int dt = 0; dt < 8; ++dt)
      bfr[dt] = *(const short8v*)(VB +
          (size_t)((((h * 7 + ks) * 8 + dt) * 64 + lane)) * 8);
    for (int sjt = 0; sjt < njt; ++sjt) {
      union { uint4 q; short8v v; } af;
      if (kb < NV) {
        const float* s2p = s2base + jmem[sjt] * NV + kb;
        float4 sa = *(const float4*)(s2p);
        float4 sb = *(const float4*)(s2p + 4);
        float4 ta = *(const float4*)&s1s[kb];
        float4 tb = *(const float4*)&s1s[kb + 4];
        float cr = Crow[sjt];
        float p0 = exp2f(ta.x + sa.x - cr);
        float p1 = exp2f(ta.y + sa.y - cr);
        float p2 = exp2f(ta.z + sa.z - cr);
        float p3 = exp2f(ta.w + sa.w - cr);
        float p4 = exp2f(tb.x + sb.x - cr);
        float p5 = exp2f(tb.y + sb.y - cr);
        float p6 = exp2f(tb.z + sb.z - cr);
        float p7 = exp2f(tb.w + sb.w - cr);
        af.q.x = packbf(p0, p1);
        af.q.y = packbf(p2, p3);
        af.q.z = packbf(p4, p5);
        af.q.w = packbf(p6, p7);
      } else {
        af.q = make_uint4(0, 0, 0, 0);
      }
#pragma unroll
      for (int dt = 0; dt < 8; ++dt)
        acc[sjt][dt] = __builtin_amdgcn_mfma_f32_16x16x32_bf16(
            af.v, bfr[dt], acc[sjt][dt], 0, 0, 0);
    }
  }
  // store: OT row (h,i,j) fully covered d=0..127 (d>=118 is exact 0 from VB pad)
  for (int sjt = 0; sjt < njt; ++sjt) {
    int jt = wv + sjt * 4;
#pragma unroll
    for (int r2 = 0; r2 < 4; ++r2) {
      int rl = jt * 16 + quad * 4 + r2;
      if (rl < 100) {
        int j = jh * 100 + rl;
        size_t rowb = ((size_t)(h * NV + i) * NV + j) * 128;
#pragma unroll
        for (int dt = 0; dt < 8; ++dt)
          OT[rowb + dt * 16 + m] = f2bf(acc[sjt][dt][r2]);
      }
    }
  }
}

// ---------------------------------------------------------------------------
// E2: w3T[c][k'] bf16, k' = h*128+d (zero-padded d>=118, c>=472). 512x512.
// ---------------------------------------------------------------------------
__global__ __launch_bounds__(256) void k_w3T(
    const float* __restrict__ w3, ushort* __restrict__ w3T) {
  int idx = blockIdx.x * 256 + threadIdx.x;  // < 512*512
  if (idx < 512 * 512) {
    int c = idx >> 9, kp = idx & 511;
    int h = kp >> 7, d = kp & 127;
    ushort v = 0;
    if (c < DM && d < HD) v = f2bf(w3[(h * HD + d) * DM + c]);
    w3T[idx] = v;
  }
}

// ---------------------------------------------------------------------------
// F: S = (O + O^T_mirror) @ w3 + 2*b3 via bf16 MFMA over padded K'=512.
// Mirror-add fused into the A-staging (k_osum eliminated).
// ---------------------------------------------------------------------------
__global__ __launch_bounds__(256) void k_sgemm(
    const ushort* __restrict__ OT, const ushort* __restrict__ w3T,
    const float* __restrict__ b3, float* __restrict__ outS) {
  __shared__ __align__(16) ushort As[128 * 40];
  __shared__ __align__(16) ushort Bs[128 * 40];
  int t = threadIdx.x;
  int c0 = blockIdx.x * 128, b0 = blockIdx.y * 128;
  int r = t >> 1, kh = (t & 1) * 16;
  int lane = t & 63, wv = t >> 6;
  int wm = wv & 1, wn = wv >> 1;
  int frow = lane & 15, quad = lane >> 4;
  int gr = b0 + r;
  int ii = 0, jj = 0;
  bool valid = (gr < NN);
  if (valid) { ii = gr / NV; jj = gr - ii * NV; }
  float4v acc[4][4];
#pragma unroll
  for (int m = 0; m < 4; m++)
#pragma unroll
    for (int n = 0; n < 4; n++) acc[m][n] = (float4v)(0.f);

  for (int step = 0; step < 16; ++step) {
    int k0 = step * 32;
    int gk = k0 + kh;              // k' in [0,512)
    int hh = gk >> 7, dd = gk & 127;
    // B tile regs (w3T padded — always safe)
    const uint4* wp = (const uint4*)(w3T + (size_t)(c0 + r) * 512 + gk);
    uint4 bq0 = wp[0], bq1 = wp[1];
    // A tile regs: bf16(OT[h][i][j][dd..+16] + OT[h][j][i][dd..+16])
    uint4 aq0 = make_uint4(0, 0, 0, 0), aq1 = aq0;
    if (valid) {
      const uint4* pa = (const uint4*)(OT +
          (((size_t)(hh * NV + ii)) * NV + jj) * 128 + dd);
      const uint4* pb = (const uint4*)(OT +
          (((size_t)(hh * NV + jj)) * NV + ii) * 128 + dd);
      uint4 qa0 = pa[0], qa1 = pa[1];
      uint4 qb0 = pb[0], qb1 = pb[1];
      aq0.x = addbf2(qa0.x, qb0.x); aq0.y = addbf2(qa0.y, qb0.y);
      aq0.z = addbf2(qa0.z, qb0.z); aq0.w = addbf2(qa0.w, qb0.w);
      aq1.x = addbf2(qa1.x, qb1.x); aq1.y = addbf2(qa1.y, qb1.y);
      aq1.z = addbf2(qa1.z, qb1.z); aq1.w = addbf2(qa1.w, qb1.w);
    }
    __syncthreads();
    *(uint4*)&As[r * 40 + kh] = aq0;
    *(uint4*)&As[r * 40 + kh + 8] = aq1;
    *(uint4*)&Bs[r * 40 + kh] = bq0;
    *(uint4*)&Bs[r * 40 + kh + 8] = bq1;
    __syncthreads();
    short8v af[4], bf[4];
#pragma unroll
    for (int m = 0; m < 4; m++)
      af[m] = *(const short8v*)&As[(wm * 64 + m * 16 + frow) * 40 + quad * 8];
#pragma unroll
    for (int n = 0; n < 4; n++)
      bf[n] = *(const short8v*)&Bs[(wn * 64 + n * 16 + frow) * 40 + quad * 8];
#pragma unroll
    for (int m = 0; m < 4; m++)
#pragma unroll
      for (int n = 0; n < 4; n++)
        acc[m][n] = __builtin_amdgcn_mfma_f32_16x16x32_bf16(af[m], bf[n],
                                                            acc[m][n], 0, 0, 0);
  }
  int col = lane & 15;
#pragma unroll
  for (int n = 0; n < 4; n++) {
    int c = c0 + wn * 64 + n * 16 + col;
    if (c >= DM) continue;
    float bb = 2.0f * b3[c];
#pragma unroll
    for (int m = 0; m < 4; m++) {
      int bbase = b0 + wm * 64 + m * 16 + quad * 4;
#pragma unroll
      for (int r2 = 0; r2 < 4; r2++) {
        int b = bbase + r2;
        if (b < NN) outS[(size_t)b * DM + c] = acc[m][n][r2] + bb;
      }
    }
  }
}

// ---------------------------------------------------------------------------
// G: Q_sa = relu(S@v1+b1)@v2 + b2
// ---------------------------------------------------------------------------
__global__ __launch_bounds__(256) void k_qsa(
    const float* __restrict__ S, const float* __restrict__ v1w,
    const float* __restrict__ v1b, const float* __restrict__ v2w,
    const float* __restrict__ v2b, float* __restrict__ outQ) {
  __shared__ float Ss[64][9];
  __shared__ float V1s[8][48];
  __shared__ float Ts[64][49];
  int t = threadIdx.x;
  int b0 = blockIdx.x * 64;
  int ty = t >> 4, tx = t & 15;
  int lr = t >> 2, lk = (t & 3) * 2;
  float acc[4][3];
#pragma unroll
  for (int y = 0; y < 4; y++)
#pragma unroll
    for (int xx = 0; xx < 3; xx++) acc[y][xx] = 0.f;
  for (int k0 = 0; k0 < DM; k0 += 8) {
    __syncthreads();
    Ss[lr][lk] = S[(size_t)(b0 + lr) * DM + k0 + lk];
    Ss[lr][lk + 1] = S[(size_t)(b0 + lr) * DM + k0 + lk + 1];
    if (t < 192) {
      int e = t * 2; int kk = e / 48, c = e - kk * 48;
      V1s[kk][c] = v1w[(k0 + kk) * 48 + c];
      V1s[kk][c + 1] = v1w[(k0 + kk) * 48 + c + 1];
    }
    __syncthreads();
#pragma unroll
    for (int kk = 0; kk < 8; kk++) {
      float a0 = Ss[ty * 4 + 0][kk], a1 = Ss[ty * 4 + 1][kk],
            a2 = Ss[ty * 4 + 2][kk], a3 = Ss[ty * 4 + 3][kk];
      float w0_ = V1s[kk][tx * 3 + 0], w1_ = V1s[kk][tx * 3 + 1],
            w2_ = V1s[kk][tx * 3 + 2];
      acc[0][0] += a0 * w0_; acc[0][1] += a0 * w1_; acc[0][2] += a0 * w2_;
      acc[1][0] += a1 * w0_; acc[1][1] += a1 * w1_; acc[1][2] += a1 * w2_;
      acc[2][0] += a2 * w0_; acc[2][1] += a2 * w1_; acc[2][2] += a2 * w2_;
      acc[3][0] += a3 * w0_; acc[3][1] += a3 * w1_; acc[3][2] += a3 * w2_;
    }
  }
#pragma unroll
  for (int y = 0; y < 4; y++)
#pragma unroll
    for (int xx = 0; xx < 3; xx++)
      Ts[ty * 4 + y][tx * 3 + xx] = fmaxf(acc[y][xx] + v1b[tx * 3 + xx], 0.f);
  __syncthreads();
  if (t < 64) {
    float q = v2b[0];
    for (int c = 0; c < 48; c++) q += Ts[t][c] * v2w[c];
    outQ[b0 + t] = q;
  }
}

// ---------------------------------------------------------------------------
extern "C" void kernel_launch(void* const* d_in, const int* in_sizes, int n_in,
                              void* d_out, int out_size, void* d_ws,
                              size_t ws_size, hipStream_t stream) {
  const float* x = (const float*)d_in[0];
  const float* label = (const float*)d_in[1];
  const float* h0 = (const float*)d_in[2];
  const float* w = (const float*)d_in[3];
  const float* dmat = (const float*)d_in[4];
  const float* l0w = (const float*)d_in[5];
  const float* l0b = (const float*)d_in[6];
  const float* l1w = (const float*)d_in[7];
  const float* l1b = (const float*)d_in[8];
  const float* l2w = (const float*)d_in[9];
  const float* l2b = (const float*)d_in[10];
  const float* l3w = (const float*)d_in[11];
  const float* l3b = (const float*)d_in[12];
  const float* l4w = (const float*)d_in[13];
  const float* l4b = (const float*)d_in[14];
  const float* l5w = (const float*)d_in[15];
  const float* l5b = (const float*)d_in[16];
  const float* w0 = (const float*)d_in[17];
  const float* b0v = (const float*)d_in[18];
  const float* w1 = (const float*)d_in[19];
  const float* b1v = (const float*)d_in[20];
  const float* w3 = (const float*)d_in[21];
  const float* b3 = (const float*)d_in[22];
  const float* v1w = (const float*)d_in[23];
  const float* v1b = (const float*)d_in[24];
  const float* v2w = (const float*)d_in[25];
  const float* v2b = (const float*)d_in[26];
  const int* remain_step = (const int*)d_in[29];

  float* ws = (float*)d_ws;
  float* base = ws + WS_BASE;
  float* h1 = ws + WS_H1;
  float* h2 = ws + WS_H2;
  float* hfull = ws + WS_HFULL;
  float* gmean = ws + WS_GMEAN;
  float* W0s = ws + WS_W0S;
  float* W1s = ws + WS_W1S;
  float* khf = ws + WS_KHF;
  float* vhf = ws + WS_VHF;
  float* B1 = ws + WS_B1;
  float* B2 = ws + WS_B2;
  float* SC1 = ws + WS_SC1;
  float* SC2 = ws + WS_SC2;
  ushort* OT = (ushort*)(ws + WS_OT);
  ushort* w3T = (ushort*)(ws + WS_SC1);   // reuses SC1 slot after k_attn2
  ushort* VB = (ushort*)(ws + WS_W0S);    // reuses W0s/W1s slots after k_kv
  float* C = ws + WS_B1;                  // reuses B1/B2 slots after k_SC

  float* outS = (float*)d_out;
  float* outH = outS + OFF_H;
  float* outHF = outS + OFF_HF;
  float* outQ = outS + OFF_Q;

  k_base<<<NV, 256, 0, stream>>>(x, dmat, label, l0w, l0b, l1w, l1b, l2b, l3b,
                                 l4w, l4b, l5w, l5b, base);
  k_gcn<<<NV, 192, 0, stream>>>(h0, base, w, l2w, l3w, h1);
  k_gcn<<<NV, 192, 0, stream>>>(h1, base, w, l2w, l3w, h2);
  k_hfull<<<NV, 128, 0, stream>>>(h2, x, label, remain_step, hfull, outH, outHF);
  k_gmean<<<KG, 128, 0, stream>>>(hfull, gmean);
  k_wsum<<<(HD * DM + 255) / 256, 256, 0, stream>>>(w0, w1, W0s, W1s);
  k_kv<<<NV, 256, 0, stream>>>(hfull, W0s, b0v, W1s, b1v, khf, vhf);
  k_vhB<<<(NH * 7 * 8 * 64 + 255) / 256, 256, 0, stream>>>(vhf, VB);
  k_B<<<NV, 256, 0, stream>>>(hfull, gmean, w0, b0v, B1, B2);
  k_SC<<<NV, 256, 0, stream>>>(B1, B2, khf, SC1, SC2);
  k_ml<<<dim3(NV, NH), 256, 0, stream>>>(SC1, SC2, C);
  k_attn2<<<dim3(NV, NH, 2), 256, 0, stream>>>(SC1, SC2, C, VB, OT);
  k_w3T<<<1024, 256, 0, stream>>>(w3, w3T);
  k_sgemm<<<dim3(4, 313), 256, 0, stream>>>(OT, w3T, b3, outS);
  k_qsa<<<NN / 64, 256, 0, stream>>>(outS, v1w, v1b, v2w, v2b, outQ);
}

// Round 5
// 608.898 us; speedup vs baseline: 2.4645x; 1.2917x over previous
//
#include <hip/hip_runtime.h>
#include <hip/hip_bf16.h>
#include <math.h>

typedef unsigned short ushort;
typedef unsigned int uint;

// Sizes (fixed by the reference problem)
#define NV 200     // N nodes
#define DEG 199
#define HID 96
#define KG 20      // groups / one-hot width
#define MG 10      // group size
#define AJR 30
#define NH 4
#define HD 118     // HID + 2 + K
#define DM 472     // NH*HD
#define NN 40000   // N*N

// Workspace layout (float units).
#define WS_BASE   0
#define WS_H1     19200
#define WS_H2     38400
#define WS_HFULL  57600
#define WS_GMEAN  81200
#define WS_W0S    83560
#define WS_W1S    139256
#define WS_KHF    194952
#define WS_VHF    289352
#define WS_B1     383752  // after k_SC: reused for C (softmax row consts, 160000 floats)
#define WS_B2     478152
#define WS_SC1    572552
#define WS_SC2    732552
#define WS_Z      892552             // Z fp32: 4*224*472 = 422,912 floats
#define WS_ZT     1315464            // ZT bf16: 512*896 ushorts = 229,376 floats

// Output layout (floats)
#define OFF_H   18880000
#define OFF_HF  18899200
#define OFF_Q   18922800

typedef __attribute__((ext_vector_type(8))) short short8v;
typedef __attribute__((ext_vector_type(4))) float float4v;

__device__ __forceinline__ float bf2f(uint u) {
  return __uint_as_float(u << 16);
}
__device__ __forceinline__ ushort f2bf(float f) {
  uint u = __float_as_uint(f);
  uint r = (u + 0x7fffu + ((u >> 16) & 1u)) >> 16;  // RNE
  return (ushort)r;
}
__device__ __forceinline__ uint packbf(float a, float b) {
  __hip_bfloat162 h2 = __float22bfloat162_rn(make_float2(a, b));
  union { __hip_bfloat162 h; uint u; } c;
  c.h = h2;
  return c.u;
}

// ---------------------------------------------------------------------------
// A: iteration-invariant part of the GCN update
// ---------------------------------------------------------------------------
__global__ __launch_bounds__(256) void k_base(
    const float* __restrict__ x, const float* __restrict__ dmat,
    const float* __restrict__ label,
    const float* __restrict__ l0w, const float* __restrict__ l0b,
    const float* __restrict__ l1w, const float* __restrict__ l1b,
    const float* __restrict__ l2b, const float* __restrict__ l3b,
    const float* __restrict__ l4w, const float* __restrict__ l4b,
    const float* __restrict__ l5w, const float* __restrict__ l5b,
    float* __restrict__ base) {
  int i = blockIdx.x; int t = threadIdx.x;
  int g = i / MG;
  __shared__ float sv[256];
  __shared__ float sn2[9];
  float v = -1.0f;
  if (t < DEG) {
    int u = (t < i) ? t : t + 1;
    if (u / MG != g) v = dmat[i * DEG + t];
  }
  sv[t] = v;
  __syncthreads();
  for (int k2 = 2; k2 <= 256; k2 <<= 1) {
    for (int jj = k2 >> 1; jj > 0; jj >>= 1) {
      int ixj = t ^ jj;
      if (ixj > t) {
        float a = sv[t], b = sv[ixj];
        bool sw = ((t & k2) == 0) ? (a < b) : (a > b);
        if (sw) { sv[t] = b; sv[ixj] = a; }
      }
      __syncthreads();
    }
  }
  if (t == 0) {
    float tmp[9];
    for (int q = 0; q < 9; q++) tmp[q] = dmat[i * DEG + MG * g + q];
    for (int a2 = 1; a2 < 9; a2++) {
      float key = tmp[a2]; int b2 = a2 - 1;
      while (b2 >= 0 && tmp[b2] < key) { tmp[b2 + 1] = tmp[b2]; b2--; }
      tmp[b2 + 1] = key;
    }
    for (int q = 0; q < 9; q++) sn2[q] = tmp[q];
  }
  __syncthreads();
  if (t < HID) {
    float acc = l0b[t] + l1b[t] + l2b[t] + l3b[t] + l4b[t] + l5b[t];
    acc += x[i * 2 + 0] * l0w[t] + x[i * 2 + 1] * l0w[HID + t];
    for (int k = 0; k < KG; k++) acc += label[i * KG + k] * l1w[k * HID + t];
    for (int q = 0; q < AJR; q++) acc += sv[q] * l4w[q * HID + t];
    for (int q = 0; q < 9; q++) acc += sn2[q] * l5w[q * HID + t];
    base[i * HID + t] = acc;
  }
}

// ---------------------------------------------------------------------------
// B: one GCN step
// ---------------------------------------------------------------------------
__global__ __launch_bounds__(192) void k_gcn(
    const float* __restrict__ hin, const float* __restrict__ base,
    const float* __restrict__ w, const float* __restrict__ l2w,
    const float* __restrict__ l3w, float* __restrict__ hout) {
  int i = blockIdx.x; int t = threadIdx.x;
  int g = i / MG;
  __shared__ float n1[HID], n2[HID];
  if (t < HID) {
    float acc = 0.f, wsum = 0.f;
    for (int j = 0; j < DEG; j++) {
      int u = (j < i) ? j : j + 1;
      if (u / MG != g) {
        float wj = w[i * DEG + j];
        acc += wj * hin[u * HID + t];
        wsum += wj;
      }
    }
    n1[t] = acc / wsum;
  } else if (t < 2 * HID) {
    int dd = t - HID;
    float acc = 0.f, wsum = 0.f;
    for (int u = MG * g; u < MG * g + MG; u++) {
      if (u == i) continue;
      int j = (u < i) ? u : u - 1;
      float wj = w[i * DEG + j];
      acc += wj * hin[u * HID + dd];
      wsum += wj;
    }
    n2[dd] = acc / wsum;
  }
  __syncthreads();
  if (t < HID) {
    float acc = base[i * HID + t];
    for (int dd = 0; dd < HID; dd++)
      acc += n1[dd] * l2w[dd * HID + t] + n2[dd] * l3w[dd * HID + t];
    hout[i * HID + t] = fmaxf(acc, 0.f);
  }
}

// ---------------------------------------------------------------------------
// C1: h_full assembly (+ h, h_full outputs)
// ---------------------------------------------------------------------------
__global__ __launch_bounds__(128) void k_hfull(
    const float* __restrict__ h, const float* __restrict__ x,
    const float* __restrict__ label, const int* __restrict__ remain_step,
    float* __restrict__ hfull, float* __restrict__ out_h,
    float* __restrict__ out_hf) {
  int i = blockIdx.x; int t = threadIdx.x;
  if (t < HD) {
    float v;
    if (t < HID) {
      int p = *remain_step;
      int t2 = t & ~1;
      float div = expf(-(float)t2 * (logf(10000.f) / (float)HID));
      float ang = (float)p * div;
      float pe = (t & 1) ? cosf(ang) : sinf(ang);
      float hv = h[i * HID + t];
      out_h[i * HID + t] = hv;
      v = hv + pe;
    } else if (t < HID + 2) {
      v = x[i * 2 + (t - HID)];
    } else {
      v = label[i * KG + (t - HID - 2)];
    }
    hfull[i * HD + t] = v;
    out_hf[i * HD + t] = v;
  }
}

// C2: group means of h_full
__global__ __launch_bounds__(128) void k_gmean(
    const float* __restrict__ hfull, float* __restrict__ gmean) {
  int g = blockIdx.x; int t = threadIdx.x;
  if (t < HD) {
    float s = 0.f;
    for (int q = 0; q < MG; q++) s += hfull[(g * MG + q) * HD + t];
    gmean[g * HD + t] = s * 0.1f;
  }
}

// D1: sum of the 4 118-row blocks of mha_w{0,1}
__global__ __launch_bounds__(256) void k_wsum(
    const float* __restrict__ w0, const float* __restrict__ w1,
    float* __restrict__ W0s, float* __restrict__ W1s) {
  int idx = blockIdx.x * blockDim.x + threadIdx.x;
  if (idx < HD * DM) {
    int dp = idx / DM, c = idx - dp * DM;
    W0s[idx] = w0[dp * DM + c] + w0[(HD + dp) * DM + c] +
               w0[(2 * HD + dp) * DM + c] + w0[(3 * HD + dp) * DM + c];
    W1s[idx] = w1[dp * DM + c] + w1[(HD + dp) * DM + c] +
               w1[(2 * HD + dp) * DM + c] + w1[(3 * HD + dp) * DM + c];
  }
}

// D2: khf / vhf
__global__ __launch_bounds__(256) void k_kv(
    const float* __restrict__ hfull, const float* __restrict__ W0s,
    const float* __restrict__ b0v, const float* __restrict__ W1s,
    const float* __restrict__ b1v, float* __restrict__ khf,
    float* __restrict__ vhf) {
  int i = blockIdx.x; int t = threadIdx.x;
  __shared__ float hr[HD];
  if (t < HD) hr[t] = hfull[i * HD + t];
  __syncthreads();
  for (int c = t; c < DM; c += 256) {
    float a0 = b0v[c], a1 = b1v[c];
    for (int dd = 0; dd < HD; dd++) {
      float hv = hr[dd];
      a0 += hv * W0s[dd * DM + c];
      a1 += hv * W1s[dd * DM + c];
    }
    khf[i * DM + c] = a0;
    vhf[i * DM + c] = a1;
  }
}

// D3: B1/B2 (query decomposition)
__global__ __launch_bounds__(256) void k_B(
    const float* __restrict__ hfull, const float* __restrict__ gmean,
    const float* __restrict__ w0, const float* __restrict__ b0v,
    float* __restrict__ B1, float* __restrict__ B2) {
  int i = blockIdx.x; int t = threadIdx.x; int g = i / MG;
  __shared__ float hr[HD], gr[HD];
  if (t < HD) { hr[t] = hfull[i * HD + t]; gr[t] = gmean[g * HD + t]; }
  __syncthreads();
  for (int c = t; c < DM; c += 256) {
    float a1 = 0.f, a2 = b0v[c];
    for (int dd = 0; dd < HD; dd++) {
      a1 += hr[dd] * w0[dd * DM + c] + gr[dd] * w0[(2 * HD + dd) * DM + c];
      a2 += hr[dd] * w0[(HD + dd) * DM + c] + gr[dd] * w0[(3 * HD + dd) * DM + c];
    }
    B1[i * DM + c] = a1;
    B2[i * DM + c] = a2;
  }
}

// D4: score components SC1/SC2, pre-scaled by (1/sqrt(HD))*log2(e)
__global__ __launch_bounds__(256) void k_SC(
    const float* __restrict__ B1, const float* __restrict__ B2,
    const float* __restrict__ khf, float* __restrict__ SC1,
    float* __restrict__ SC2) {
  int i = blockIdx.x; int t = threadIdx.x;
  const float scl = 1.4426950408889634f / sqrtf((float)HD);
  __shared__ float b1r[DM], b2r[DM];
  for (int c = t; c < DM; c += 256) { b1r[c] = B1[i * DM + c]; b2r[c] = B2[i * DM + c]; }
  __syncthreads();
  for (int p = t; p < NH * NV; p += 256) {
    int h = p / NV, k = p - h * NV;
    float s1a = 0.f, s2a = 0.f;
    for (int dd = 0; dd < HD; dd++) {
      float kv = khf[k * DM + h * HD + dd];
      s1a += b1r[h * HD + dd] * kv;
      s2a += b2r[h * HD + dd] * kv;
    }
    SC1[h * NN + i * NV + k] = s1a * scl;
    SC2[h * NN + i * NV + k] = s2a * scl;
  }
}

// D5: softmax row constants C[h][i][j] = m + log2(l), coalesced row scans.
__global__ __launch_bounds__(256) void k_ml(
    const float* __restrict__ SC1, const float* __restrict__ SC2,
    float* __restrict__ C) {
  int i = blockIdx.x, h = blockIdx.y;
  int t = threadIdx.x;
  __shared__ float s1s[224];
  for (int k = t; k < 224; k += 256)
    s1s[k] = (k < NV) ? SC1[h * NN + i * NV + k] : -1e30f;
  __syncthreads();
  int l = t & 31;
  int g = t >> 5;
  const float* s2b = SC2 + h * NN;
  for (int it = 0; it < 25; ++it) {
    int j = it * 8 + g;
    const float* row = s2b + j * NV;
    float v[7];
#pragma unroll
    for (int e = 0; e < 7; ++e) {
      int k = l + 32 * e;
      v[e] = (k < NV) ? (s1s[k] + row[k]) : -1e30f;
    }
    float m = v[0];
#pragma unroll
    for (int e = 1; e < 7; ++e) m = fmaxf(m, v[e]);
#pragma unroll
    for (int off = 16; off > 0; off >>= 1) m = fmaxf(m, __shfl_xor(m, off, 32));
    float s = 0.f;
#pragma unroll
    for (int e = 0; e < 7; ++e) s += exp2f(v[e] - m);
#pragma unroll
    for (int off = 16; off > 0; off >>= 1) s += __shfl_xor(s, off, 32);
    if (l == 0) C[h * NN + i * NV + j] = m + log2f(s);
  }
}

// ---------------------------------------------------------------------------
// E1: Z[h][k][c] = sum_d vhf[k][h*HD+d] * w3[(h*HD+d)*DM + c]  (fp32)
// Grid (NV, NH).
// ---------------------------------------------------------------------------
__global__ __launch_bounds__(256) void k_Z(
    const float* __restrict__ vhf, const float* __restrict__ w3,
    float* __restrict__ Z) {
  int k = blockIdx.x, h = blockIdx.y;
  int t = threadIdx.x;
  __shared__ float vr[HD];
  if (t < HD) vr[t] = vhf[k * DM + h * HD + t];
  __syncthreads();
  for (int c = t; c < DM; c += 256) {
    float a = 0.f;
    for (int d = 0; d < HD; ++d) a += vr[d] * w3[(h * HD + d) * DM + c];
    Z[((size_t)h * 224 + k) * DM + c] = a;
  }
}

// E2: ZT[c][h*224+kk] = bf16(Z[h][kk][c]) zero-padded (c>=472 or kk>=200). 512x896.
__global__ __launch_bounds__(256) void k_ZT(
    const float* __restrict__ Z, ushort* __restrict__ ZT) {
  int idx = blockIdx.x * 256 + threadIdx.x;  // < 512*896
  if (idx < 512 * 896) {
    int c = idx / 896, kp = idx - c * 896;
    int h = kp / 224, kk = kp - h * 224;
    ushort v = 0;
    if (c < DM && kk < NV) v = f2bf(Z[((size_t)h * 224 + kk) * DM + c]);
    ZT[idx] = v;
  }
}

// ---------------------------------------------------------------------------
// F: fused attention+output GEMM:
// S[b=(i,j)][c] = sum_{h,k} [exp2(SC1[h,i,k]+SC2[h,j,k]-C[h,i,j])
//                          + exp2(SC1[h,j,k]+SC2[h,i,k]-C[h,j,i])] * Z[h][k][c]
//               + 2*b3[c]
// A-fragments generated in-register by the lanes that feed the MFMA.
// 128x128 tile; 4 waves, each owning 32 b-rows (wm=wave) x all 128 cols.
// K' = 4 heads x 224 (zero-padded) = 896, stepped 32 at a time.
// ---------------------------------------------------------------------------
__global__ __launch_bounds__(256) void k_sfused(
    const float* __restrict__ SC1, const float* __restrict__ SC2,
    const float* __restrict__ C, const ushort* __restrict__ ZT,
    const float* __restrict__ b3, float* __restrict__ outS) {
  int t = threadIdx.x;
  int c0 = blockIdx.x * 128, b0 = blockIdx.y * 128;
  int lane = t & 63, wm = t >> 6;
  int frow = lane & 15, quad = lane >> 4;
  __shared__ __align__(16) ushort Bs[128 * 40];
  __shared__ __align__(16) float S1i[2][224];
  __shared__ __align__(16) float S2i[2][224];
  __shared__ float Cij[128], Cji[128];
  int i0 = b0 / NV;
  int i1 = (b0 + 127) / NV; if (i1 >= NV) i1 = NV - 1;
  // this lane's two rows
  int rr[2], jj[2], isel[2]; bool bval[2];
#pragma unroll
  for (int m = 0; m < 2; ++m) {
    rr[m] = wm * 32 + m * 16 + frow;
    int b = b0 + rr[m];
    bval[m] = (b < NN);
    int ii = bval[m] ? (b / NV) : 0;
    jj[m] = bval[m] ? (b - ii * NV) : 0;
    isel[m] = bval[m] ? (ii - i0) : 0;
  }
  float4v acc[2][8];
#pragma unroll
  for (int m = 0; m < 2; ++m)
#pragma unroll
    for (int n = 0; n < 8; ++n) acc[m][n] = (float4v)(0.f);
  int rB = t >> 1, khB = (t & 1) * 16;

  for (int h = 0; h < NH; ++h) {
    __syncthreads();  // all waves done with previous phase's S1i/S2i/Cij
    for (int e = t; e < 224; e += 256) {
      bool v = (e < NV);
      S1i[0][e] = v ? SC1[h * NN + i0 * NV + e] : 0.f;
      S2i[0][e] = v ? SC2[h * NN + i0 * NV + e] : 0.f;
      S1i[1][e] = v ? SC1[h * NN + i1 * NV + e] : 0.f;
      S2i[1][e] = v ? SC2[h * NN + i1 * NV + e] : 0.f;
    }
    for (int e = t; e < 128; e += 256) {
      int b = b0 + e;
      if (b < NN) {
        int ii = b / NV, jv = b - ii * NV;
        Cij[e] = C[h * NN + b];
        Cji[e] = C[h * NN + jv * NV + ii];
      } else {
        Cij[e] = 0.f; Cji[e] = 0.f;
      }
    }
    __syncthreads();
    float ci[2], cj[2];
    const float* pj1[2]; const float* pj2[2];
#pragma unroll
    for (int m = 0; m < 2; ++m) {
      ci[m] = Cij[rr[m]];
      cj[m] = Cji[rr[m]];
      pj1[m] = SC1 + h * NN + jj[m] * NV;
      pj2[m] = SC2 + h * NN + jj[m] * NV;
    }
    for (int ks = 0; ks < 7; ++ks) {
      int kb = ks * 32 + quad * 8;
      bool kvalid = (kb + 7 < NV);  // uniform per (ks,quad); ks=6,quad=0 -> 192..199 ok
      // --- generate A fragments in-register ---
      union { uint4 q; short8v v; } af[2];
#pragma unroll
      for (int m = 0; m < 2; ++m) {
        if (bval[m] && kvalid) {
          float4 a1 = *(const float4*)(pj1[m] + kb);
          float4 a1b = *(const float4*)(pj1[m] + kb + 4);
          float4 a2 = *(const float4*)(pj2[m] + kb);
          float4 a2b = *(const float4*)(pj2[m] + kb + 4);
          float4 t1 = *(const float4*)&S1i[isel[m]][kb];
          float4 t1b = *(const float4*)&S1i[isel[m]][kb + 4];
          float4 u1 = *(const float4*)&S2i[isel[m]][kb];
          float4 u1b = *(const float4*)&S2i[isel[m]][kb + 4];
          float cim = ci[m], cjm = cj[m];
          float p0 = exp2f(t1.x + a2.x - cim) + exp2f(a1.x + u1.x - cjm);
          float p1 = exp2f(t1.y + a2.y - cim) + exp2f(a1.y + u1.y - cjm);
          float p2 = exp2f(t1.z + a2.z - cim) + exp2f(a1.z + u1.z - cjm);
          float p3 = exp2f(t1.w + a2.w - cim) + exp2f(a1.w + u1.w - cjm);
          float p4 = exp2f(t1b.x + a2b.x - cim) + exp2f(a1b.x + u1b.x - cjm);
          float p5 = exp2f(t1b.y + a2b.y - cim) + exp2f(a1b.y + u1b.y - cjm);
          float p6 = exp2f(t1b.z + a2b.z - cim) + exp2f(a1b.z + u1b.z - cjm);
          float p7 = exp2f(t1b.w + a2b.w - cim) + exp2f(a1b.w + u1b.w - cjm);
          af[m].q.x = packbf(p0, p1);
          af[m].q.y = packbf(p2, p3);
          af[m].q.z = packbf(p4, p5);
          af[m].q.w = packbf(p6, p7);
        } else {
          af[m].q = make_uint4(0, 0, 0, 0);
        }
      }
      // --- stage B tile (Z^T slice) ---
      const uint4* wp = (const uint4*)(ZT + (size_t)(c0 + rB) * 896 +
                                       h * 224 + ks * 32 + khB);
      uint4 bq0 = wp[0], bq1 = wp[1];
      __syncthreads();
      *(uint4*)&Bs[rB * 40 + khB] = bq0;
      *(uint4*)&Bs[rB * 40 + khB + 8] = bq1;
      __syncthreads();
      // --- MFMA ---
#pragma unroll
      for (int n = 0; n < 8; ++n) {
        short8v bf = *(const short8v*)&Bs[(n * 16 + frow) * 40 + quad * 8];
        acc[0][n] = __builtin_amdgcn_mfma_f32_16x16x32_bf16(af[0].v, bf,
                                                            acc[0][n], 0, 0, 0);
        acc[1][n] = __builtin_amdgcn_mfma_f32_16x16x32_bf16(af[1].v, bf,
                                                            acc[1][n], 0, 0, 0);
      }
    }
  }
  // epilogue: C/D layout col=lane&15, row=quad*4+reg
#pragma unroll
  for (int n = 0; n < 8; ++n) {
    int c = c0 + n * 16 + frow;
    if (c >= DM) continue;
    float bb = 2.0f * b3[c];
#pragma unroll
    for (int m = 0; m < 2; ++m) {
      int bbase = b0 + wm * 32 + m * 16 + quad * 4;
#pragma unroll
      for (int r2 = 0; r2 < 4; ++r2) {
        int b = bbase + r2;
        if (b < NN) outS[(size_t)b * DM + c] = acc[m][n][r2] + bb;
      }
    }
  }
}

// ---------------------------------------------------------------------------
// G: Q_sa = relu(S@v1+b1)@v2 + b2
// ---------------------------------------------------------------------------
__global__ __launch_bounds__(256) void k_qsa(
    const float* __restrict__ S, const float* __restrict__ v1w,
    const float* __restrict__ v1b, const float* __restrict__ v2w,
    const float* __restrict__ v2b, float* __restrict__ outQ) {
  __shared__ float Ss[64][9];
  __shared__ float V1s[8][48];
  __shared__ float Ts[64][49];
  int t = threadIdx.x;
  int b0 = blockIdx.x * 64;
  int ty = t >> 4, tx = t & 15;
  int lr = t >> 2, lk = (t & 3) * 2;
  float acc[4][3];
#pragma unroll
  for (int y = 0; y < 4; y++)
#pragma unroll
    for (int xx = 0; xx < 3; xx++) acc[y][xx] = 0.f;
  for (int k0 = 0; k0 < DM; k0 += 8) {
    __syncthreads();
    Ss[lr][lk] = S[(size_t)(b0 + lr) * DM + k0 + lk];
    Ss[lr][lk + 1] = S[(size_t)(b0 + lr) * DM + k0 + lk + 1];
    if (t < 192) {
      int e = t * 2; int kk = e / 48, c = e - kk * 48;
      V1s[kk][c] = v1w[(k0 + kk) * 48 + c];
      V1s[kk][c + 1] = v1w[(k0 + kk) * 48 + c + 1];
    }
    __syncthreads();
#pragma unroll
    for (int kk = 0; kk < 8; kk++) {
      float a0 = Ss[ty * 4 + 0][kk], a1 = Ss[ty * 4 + 1][kk],
            a2 = Ss[ty * 4 + 2][kk], a3 = Ss[ty * 4 + 3][kk];
      float w0_ = V1s[kk][tx * 3 + 0], w1_ = V1s[kk][tx * 3 + 1],
            w2_ = V1s[kk][tx * 3 + 2];
      acc[0][0] += a0 * w0_; acc[0][1] += a0 * w1_; acc[0][2] += a0 * w2_;
      acc[1][0] += a1 * w0_; acc[1][1] += a1 * w1_; acc[1][2] += a1 * w2_;
      acc[2][0] += a2 * w0_; acc[2][1] += a2 * w1_; acc[2][2] += a2 * w2_;
      acc[3][0] += a3 * w0_; acc[3][1] += a3 * w1_; acc[3][2] += a3 * w2_;
    }
  }
#pragma unroll
  for (int y = 0; y < 4; y++)
#pragma unroll
    for (int xx = 0; xx < 3; xx++)
      Ts[ty * 4 + y][tx * 3 + xx] = fmaxf(acc[y][xx] + v1b[tx * 3 + xx], 0.f);
  __syncthreads();
  if (t < 64) {
    float q = v2b[0];
    for (int c = 0; c < 48; c++) q += Ts[t][c] * v2w[c];
    outQ[b0 + t] = q;
  }
}

// ---------------------------------------------------------------------------
extern "C" void kernel_launch(void* const* d_in, const int* in_sizes, int n_in,
                              void* d_out, int out_size, void* d_ws,
                              size_t ws_size, hipStream_t stream) {
  const float* x = (const float*)d_in[0];
  const float* label = (const float*)d_in[1];
  const float* h0 = (const float*)d_in[2];
  const float* w = (const float*)d_in[3];
  const float* dmat = (const float*)d_in[4];
  const float* l0w = (const float*)d_in[5];
  const float* l0b = (const float*)d_in[6];
  const float* l1w = (const float*)d_in[7];
  const float* l1b = (const float*)d_in[8];
  const float* l2w = (const float*)d_in[9];
  const float* l2b = (const float*)d_in[10];
  const float* l3w = (const float*)d_in[11];
  const float* l3b = (const float*)d_in[12];
  const float* l4w = (const float*)d_in[13];
  const float* l4b = (const float*)d_in[14];
  const float* l5w = (const float*)d_in[15];
  const float* l5b = (const float*)d_in[16];
  const float* w0 = (const float*)d_in[17];
  const float* b0v = (const float*)d_in[18];
  const float* w1 = (const float*)d_in[19];
  const float* b1v = (const float*)d_in[20];
  const float* w3 = (const float*)d_in[21];
  const float* b3 = (const float*)d_in[22];
  const float* v1w = (const float*)d_in[23];
  const float* v1b = (const float*)d_in[24];
  const float* v2w = (const float*)d_in[25];
  const float* v2b = (const float*)d_in[26];
  const int* remain_step = (const int*)d_in[29];

  float* ws = (float*)d_ws;
  float* base = ws + WS_BASE;
  float* h1 = ws + WS_H1;
  float* h2 = ws + WS_H2;
  float* hfull = ws + WS_HFULL;
  float* gmean = ws + WS_GMEAN;
  float* W0s = ws + WS_W0S;
  float* W1s = ws + WS_W1S;
  float* khf = ws + WS_KHF;
  float* vhf = ws + WS_VHF;
  float* B1 = ws + WS_B1;
  float* B2 = ws + WS_B2;
  float* SC1 = ws + WS_SC1;
  float* SC2 = ws + WS_SC2;
  float* Z = ws + WS_Z;
  ushort* ZT = (ushort*)(ws + WS_ZT);
  float* C = ws + WS_B1;  // reuses B1/B2 slots after k_SC

  float* outS = (float*)d_out;
  float* outH = outS + OFF_H;
  float* outHF = outS + OFF_HF;
  float* outQ = outS + OFF_Q;

  k_base<<<NV, 256, 0, stream>>>(x, dmat, label, l0w, l0b, l1w, l1b, l2b, l3b,
                                 l4w, l4b, l5w, l5b, base);
  k_gcn<<<NV, 192, 0, stream>>>(h0, base, w, l2w, l3w, h1);
  k_gcn<<<NV, 192, 0, stream>>>(h1, base, w, l2w, l3w, h2);
  k_hfull<<<NV, 128, 0, stream>>>(h2, x, label, remain_step, hfull, outH, outHF);
  k_gmean<<<KG, 128, 0, stream>>>(hfull, gmean);
  k_wsum<<<(HD * DM + 255) / 256, 256, 0, stream>>>(w0, w1, W0s, W1s);
  k_kv<<<NV, 256, 0, stream>>>(hfull, W0s, b0v, W1s, b1v, khf, vhf);
  k_Z<<<dim3(NV, NH), 256, 0, stream>>>(vhf, w3, Z);
  k_ZT<<<(512 * 896 + 255) / 256, 256, 0, stream>>>(Z, ZT);
  k_B<<<NV, 256, 0, stream>>>(hfull, gmean, w0, b0v, B1, B2);
  k_SC<<<NV, 256, 0, stream>>>(B1, B2, khf, SC1, SC2);
  k_ml<<<dim3(NV, NH), 256, 0, stream>>>(SC1, SC2, C);
  k_sfused<<<dim3(4, 313), 256, 0, stream>>>(SC1, SC2, C, ZT, b3, outS);
  k_qsa<<<NN / 64, 256, 0, stream>>>(outS, v1w, v1b, v2w, v2b, outQ);
}